// Round 9
// baseline (49.651 us; speedup 1.0000x reference)
//
#include <hip/hip_runtime.h>

typedef short short8 __attribute__((ext_vector_type(8)));
typedef float f32x4 __attribute__((ext_vector_type(4)));
typedef unsigned int u32;
typedef unsigned short u16;

union PackU { u32 u[4]; short8 s8; };

__device__ __forceinline__ u16 f2bf(float f) {
  unsigned u = __builtin_bit_cast(unsigned, f);
  u = (u + 0x7FFFu + ((u >> 16) & 1u)) >> 16;
  return (u16)u;
}

__device__ __forceinline__ u32 cvt_pk_bf16(float lo, float hi) {
  u32 r;
  asm("v_cvt_pk_bf16_f32 %0, %1, %2" : "=v"(r) : "v"(lo), "v"(hi));
  return r;
}

__device__ __forceinline__ f32x4 mfma16(short8 a, short8 b, f32x4 c) {
  return __builtin_amdgcn_mfma_f32_16x16x32_bf16(a, b, c, 0, 0, 0);
}

// async global->LDS, 16B per lane, wave covers 1KB. LDS dest = uniform base.
__device__ __forceinline__ void gl_lds16(const void* g, void* l) {
  __builtin_amdgcn_global_load_lds(
      (const __attribute__((address_space(1))) u32*)g,
      (__attribute__((address_space(3))) u32*)l, 16, 0, 0);
}

// x-LDS word swizzle (fp32 words within a 64-word row); 4-aligned -> b128-safe
__device__ __forceinline__ int swzx(int r) {
  return ((r & 7) << 3) ^ ((r & 8) >> 1);
}

// scale for Wq: (1/sqrt(1024)) * log2(e)  -> scores come out in log2 domain
#define QSCALE 0.04508422619125366f

// ---------------------------------------------------------------------------
// W conversion: wcat[192][1024] bf16, PRE-SWIZZLED within each 64-col tile
// (stored col = (c&~63) | ((c&63) ^ ((row&7)<<3))) so that a linear
// global_load_lds of a [192][64] tile lands bank-conflict-free in LDS.
// rows 0..63 = Wq*QSCALE, 64..127 = Wk, 128..191 = Wv.
// ---------------------------------------------------------------------------
__global__ __launch_bounds__(256) void wconv_kernel(
    const float* __restrict__ Wk, const float* __restrict__ Wq,
    const float* __restrict__ Wv, u16* __restrict__ wcat)
{
  const int t = blockIdx.x * 256 + threadIdx.x;   // 24576 threads
  const int row = t >> 7;
  const int col = (t & 127) * 8;
  const float* src;
  float scale = 1.0f;
  if (row < 64)       { src = Wq + (size_t)row * 1024;        scale = QSCALE; }
  else if (row < 128) { src = Wk + (size_t)(row - 64) * 1024; }
  else                { src = Wv + (size_t)(row - 128) * 1024; }
  float4 a = *(const float4*)(src + col);
  float4 b = *(const float4*)(src + col + 4);
  PackU p;
  p.u[0] = cvt_pk_bf16(a.x * scale, a.y * scale);
  p.u[1] = cvt_pk_bf16(a.z * scale, a.w * scale);
  p.u[2] = cvt_pk_bf16(b.x * scale, b.y * scale);
  p.u[3] = cvt_pk_bf16(b.z * scale, b.w * scale);
  const int scol = (col & ~63) | ((col & 63) ^ ((row & 7) << 3));
  *(short8*)&wcat[(size_t)row * 1024 + scol] = p.s8;
}

// ---------------------------------------------------------------------------
// Projection: 256 blocks x 512 thr (8 waves, 2 row x 4 col). Block = 64
// tokens x 192 heads, BK=64. Staging via global_load_lds width-16 into a
// TRIPLE-buffered LDS pipeline with counted vmcnt (T3/T4): per step,
// s_waitcnt vmcnt(5) retires stage s while stage s+1 stays in flight;
// raw s_barrier (no compiler drain); stage s+2 issued after the barrier.
// W from pre-swizzled wcat (linear copy); x as fp32 with the inverse XOR
// swizzle applied to each lane's global address; f32->bf16 at fragment
// read (cvt_pk). LDS 120KB -> 1 block/CU.
// Outputs: qw,kw [8][2048][64] bf16; vtw [8][64][2048] bf16 in PERMUTED
// key order: token t stored at (t&~31)|((t>>2)&3)<<3|((t>>4)&1)<<2|(t&3).
// ---------------------------------------------------------------------------
__global__ __launch_bounds__(512, 2) void proj_kernel(
    const float* __restrict__ x, const u16* __restrict__ wcat,
    u16* __restrict__ qw, u16* __restrict__ kw, u16* __restrict__ vtw)
{
  const int tid  = threadIdx.x;
  const int lane = tid & 63;
  const int wv   = tid >> 6;
  const int lr   = lane & 15, lg = lane >> 4;
  const int wr   = wv >> 2, wc = wv & 3;   // 2x4 wave grid
  const int row0 = blockIdx.x * 64;

  __shared__ float lX[3][64 * 64];   // 3 x 16KB fp32, swizzled cols
  __shared__ u16   lW[3][192 * 64];  // 3 x 24KB bf16, swizzled cols

  // --- staging addresses (per wave: 2 x-insts + 3 W-insts, 1KB each) ---
  const int xr0 = 4 * wv + (lane >> 4);
  const int xr1 = 4 * (wv + 8) + (lane >> 4);
  const float* xg0 = x + (size_t)(row0 + xr0) * 1024 + (((lane & 15) * 4) ^ swzx(xr0));
  const float* xg1 = x + (size_t)(row0 + xr1) * 1024 + (((lane & 15) * 4) ^ swzx(xr1));
  const u16* wg0 = wcat + (size_t)(8 * wv        + (lane >> 3)) * 1024 + (lane & 7) * 8;
  const u16* wg1 = wcat + (size_t)(8 * (wv + 8)  + (lane >> 3)) * 1024 + (lane & 7) * 8;
  const u16* wg2 = wcat + (size_t)(8 * (wv + 16) + (lane >> 3)) * 1024 + (lane & 7) * 8;

  const f32x4 vzero = {0.f, 0.f, 0.f, 0.f};
  f32x4 acc[2][3];
#pragma unroll
  for (int m = 0; m < 2; ++m)
#pragma unroll
    for (int c = 0; c < 3; ++c) acc[m][c] = vzero;

  auto stage = [&](int buf, int s) {
    const int k0 = s * 64;
    gl_lds16(xg0 + k0, &lX[buf][wv * 256]);
    gl_lds16(xg1 + k0, &lX[buf][(wv + 8) * 256]);
    gl_lds16(wg0 + k0, &lW[buf][wv * 512]);
    gl_lds16(wg1 + k0, &lW[buf][(wv + 8) * 512]);
    gl_lds16(wg2 + k0, &lW[buf][(wv + 16) * 512]);
  };

  auto computeStep = [&](int buf) {
    short8 af[2][2], wf[3][2];
#pragma unroll
    for (int m = 0; m < 2; ++m) {
      const int ar = wr * 32 + m * 16 + lr;
      const int v  = swzx(ar);
#pragma unroll
      for (int ks = 0; ks < 2; ++ks) {
        const int c0 = ks * 32 + lg * 8;
        f32x4 lo = *(const f32x4*)&lX[buf][ar * 64 + (c0 ^ v)];
        f32x4 hi = *(const f32x4*)&lX[buf][ar * 64 + ((c0 + 4) ^ v)];
        PackU p;
        p.u[0] = cvt_pk_bf16(lo[0], lo[1]);
        p.u[1] = cvt_pk_bf16(lo[2], lo[3]);
        p.u[2] = cvt_pk_bf16(hi[0], hi[1]);
        p.u[3] = cvt_pk_bf16(hi[2], hi[3]);
        af[m][ks] = p.s8;
      }
    }
#pragma unroll
    for (int c = 0; c < 3; ++c) {
      const int nr = wc * 48 + c * 16 + lr;
#pragma unroll
      for (int ks = 0; ks < 2; ++ks)
        wf[c][ks] = *(const short8*)&lW[buf][nr * 64 + (((ks << 5) | (lg << 3)) ^ ((nr & 7) << 3))];
    }
#pragma unroll
    for (int m = 0; m < 2; ++m)
#pragma unroll
      for (int c = 0; c < 3; ++c) {
        acc[m][c] = mfma16(af[m][0], wf[c][0], acc[m][c]);
        acc[m][c] = mfma16(af[m][1], wf[c][1], acc[m][c]);
      }
  };

  stage(0, 0);
  stage(1, 1);
  for (int s = 0; s < 15; ++s) {
    asm volatile("s_waitcnt vmcnt(5)" ::: "memory");
    __builtin_amdgcn_s_barrier();
    __builtin_amdgcn_sched_barrier(0);
    if (s < 14) stage((s + 2) % 3, s + 2);
    computeStep(s % 3);
  }
  asm volatile("s_waitcnt vmcnt(0)" ::: "memory");
  __builtin_amdgcn_s_barrier();
  __builtin_amdgcn_sched_barrier(0);
  computeStep(0);   // step 15, buf 15%3 = 0

  const int bb = row0 >> 11;
  const int tb = row0 & 2047;
#pragma unroll
  for (int m = 0; m < 2; ++m) {
    const int tl0 = tb + wr * 32 + 16 * m + 4 * lg;
#pragma unroll
    for (int c = 0; c < 3; ++c) {
      const int n  = wc * 48 + c * 16 + lr;
      const int hd = n & 63;
      if (n < 128) {
        u16* dst = (n < 64) ? qw : kw;
#pragma unroll
        for (int r = 0; r < 4; ++r)
          dst[((size_t)(bb * 2048 + tl0 + r)) * 64 + hd] = f2bf(acc[m][c][r]);
      } else {
        const int posb = (tl0 & ~31) | (((tl0 >> 2) & 3) << 3) | (((tl0 >> 4) & 1) << 2);
        u32* dst = (u32*)&vtw[((size_t)(bb * 64 + hd)) * 2048 + posb];
        dst[0] = cvt_pk_bf16(acc[m][c][0], acc[m][c][1]);
        dst[1] = cvt_pk_bf16(acc[m][c][2], acc[m][c][3]);
      }
    }
  }
}

// ---------------------------------------------------------------------------
// Attention partials. grid = 8 batches x 80 (group,chunk) blocks, 256 thr.
// Block = q-group j (64 rows = 4 waves x 16-row strips), KV chunk of <=8
// 64-key tiles staged in LDS (dbuf, XOR-swizzled), shared by the 4 waves.
// Swapped QK (A=K, B=Q): lane holds S[key=16c+4lg+r][q=lr]. Static-max
// softmax: P = exp2(S) (Wq pre-scaled by log2e/32), per-lane scalar lsum.
// PV: A=V(perm layout), B=P packed lane-locally. Chunked groups write
// unnormalized partials; single-chunk groups (j<8) write out directly.
// ---------------------------------------------------------------------------
__global__ __launch_bounds__(256, 2) void attn_kernel(
    const u16* __restrict__ qw, const u16* __restrict__ kw,
    const u16* __restrict__ vtw, float* __restrict__ out,
    float* __restrict__ Opart, float* __restrict__ lpart)
{
  const int tid  = threadIdx.x;
  const int lane = tid & 63;
  const int sid  = tid >> 6;           // strip 0..3
  const int lr   = lane & 15, lg = lane >> 4;
  const int bid  = blockIdx.x;
  const int b    = bid / 80;
  const int g    = bid % 80;

  int j, ch, nch;
  if (g < 8)       { j = g;                ch = 0;          nch = 1; }
  else if (g < 24) { int u = g - 8;  j = 8  + (u >> 1); ch = u & 1;  nch = 2; }
  else if (g < 48) { int u = g - 24; j = 16 + u / 3;    ch = u % 3;  nch = 3; }
  else             { int u = g - 48; j = 24 + (u >> 2); ch = u & 3;  nch = 4; }
  const int kt0 = ch * 8;
  const int kt1 = (kt0 + 8 < j + 1) ? (kt0 + 8) : (j + 1);
  const int q0r = j * 64 + sid * 16;

  __shared__ u16 lK[2][64 * 64];
  __shared__ u16 lV[2][64 * 64];

  const size_t qoff = ((size_t)(b * 2048 + q0r + lr)) * 64 + lg * 8;
  const short8 qa = *(const short8*)(qw + qoff);
  const short8 qb = *(const short8*)(qw + qoff + 32);

  const f32x4 vzero = {0.f, 0.f, 0.f, 0.f};
  f32x4 o[4];
#pragma unroll
  for (int i = 0; i < 4; ++i) o[i] = vzero;
  float lsum = 0.f;

  // staging geometry: 512 chunks per matrix, 2 per thread
  const int sr0 = tid >> 3;            // 0..31 (i=1 adds 32)
  const int sc0 = (tid & 7) * 8;
  const int la0 = (sr0 * 64 + sc0) ^ ((sr0 & 7) << 3);

  short8 kst[2], vst[2];
  {
    const int kb = kt0 * 64;
#pragma unroll
    for (int i = 0; i < 2; ++i) {
      const int r = sr0 + i * 32;
      kst[i] = *(const short8*)(kw  + ((size_t)(b * 2048 + kb + r)) * 64 + sc0);
      vst[i] = *(const short8*)(vtw + ((size_t)(b * 64 + r)) * 2048 + kb + sc0);
    }
#pragma unroll
    for (int i = 0; i < 2; ++i) {
      *(short8*)&lK[0][la0 + i * 2048] = kst[i];
      *(short8*)&lV[0][la0 + i * 2048] = vst[i];
    }
  }
  __syncthreads();

  for (int kt = kt0; kt < kt1; ++kt) {
    const int cur = (kt - kt0) & 1;
    if (kt + 1 < kt1) {
      const int kb = (kt + 1) * 64;
#pragma unroll
      for (int i = 0; i < 2; ++i) {
        const int r = sr0 + i * 32;
        kst[i] = *(const short8*)(kw  + ((size_t)(b * 2048 + kb + r)) * 64 + sc0);
        vst[i] = *(const short8*)(vtw + ((size_t)(b * 64 + r)) * 2048 + kb + sc0);
      }
    }
    // QK^T (swapped): s4[c][r] = S[key = 64kt+16c+4lg+r][q = q0r+lr]
    f32x4 s4[4];
#pragma unroll
    for (int c = 0; c < 4; ++c) {
      const int row = 16 * c + lr;
      const short8 kf0 = *(const short8*)&lK[cur][(row * 64 + lg * 8) ^ ((row & 7) << 3)];
      const short8 kf1 = *(const short8*)&lK[cur][(row * 64 + 32 + lg * 8) ^ ((row & 7) << 3)];
      f32x4 z = vzero;
      z = mfma16(kf0, qa, z);
      z = mfma16(kf1, qb, z);
      s4[c] = z;
    }
    if (kt == j) {   // causal mask on the diagonal tile
#pragma unroll
      for (int c = 0; c < 4; ++c)
#pragma unroll
        for (int r = 0; r < 4; ++r)
          if (16 * c + 4 * lg + r > sid * 16 + lr) s4[c][r] = -1e30f;
    }
    // exp2 + lane-local row-sum accumulation
#pragma unroll
    for (int c = 0; c < 4; ++c)
#pragma unroll
      for (int r = 0; r < 4; ++r) {
        const float e = __builtin_amdgcn_exp2f(s4[c][r]);
        s4[c][r] = e;
        lsum += e;
      }
    // pack P lane-locally: pb0 = keys of c=0,1 ; pb1 = keys of c=2,3
    PackU p0, p1;
    p0.u[0] = cvt_pk_bf16(s4[0][0], s4[0][1]);
    p0.u[1] = cvt_pk_bf16(s4[0][2], s4[0][3]);
    p0.u[2] = cvt_pk_bf16(s4[1][0], s4[1][1]);
    p0.u[3] = cvt_pk_bf16(s4[1][2], s4[1][3]);
    p1.u[0] = cvt_pk_bf16(s4[2][0], s4[2][1]);
    p1.u[1] = cvt_pk_bf16(s4[2][2], s4[2][3]);
    p1.u[2] = cvt_pk_bf16(s4[3][0], s4[3][1]);
    p1.u[3] = cvt_pk_bf16(s4[3][2], s4[3][3]);
    const short8 pb0 = p0.s8, pb1 = p1.s8;
    // PV: o[cd] over d = 16cd+4lg+r
#pragma unroll
    for (int cd = 0; cd < 4; ++cd) {
      const int row = 16 * cd + lr;
      const short8 vf0 = *(const short8*)&lV[cur][(row * 64 + lg * 8) ^ ((row & 7) << 3)];
      const short8 vf1 = *(const short8*)&lV[cur][(row * 64 + 32 + lg * 8) ^ ((row & 7) << 3)];
      o[cd] = mfma16(vf0, pb0, o[cd]);
      o[cd] = mfma16(vf1, pb1, o[cd]);
    }
    if (kt + 1 < kt1) {
#pragma unroll
      for (int i = 0; i < 2; ++i) {
        *(short8*)&lK[cur ^ 1][la0 + i * 2048] = kst[i];
        *(short8*)&lV[cur ^ 1][la0 + i * 2048] = vst[i];
      }
      __syncthreads();
    }
  }

  lsum += __shfl_xor(lsum, 16, 64);
  lsum += __shfl_xor(lsum, 32, 64);

  if (nch == 1) {
    const float inv = 1.0f / lsum;
    float* op = out + ((size_t)(b * 2048 + q0r + lr)) * 64;
#pragma unroll
    for (int cd = 0; cd < 4; ++cd) {
      f32x4 v = o[cd] * inv;
      *(f32x4*)(op + 16 * cd + 4 * lg) = v;
    }
  } else {
    int pb;
    if (j < 16)      pb = 2 * (j - 8);
    else if (j < 24) pb = 16 + 3 * (j - 16);
    else             pb = 40 + 4 * (j - 24);
    const int pidx = b * 72 + pb + ch;
    float* op = Opart + ((size_t)(pidx * 64) + sid * 16 + lr) * 64;
#pragma unroll
    for (int cd = 0; cd < 4; ++cd)
      *(f32x4*)(op + 16 * cd + 4 * lg) = o[cd];
    if (lg == 0) lpart[pidx * 64 + sid * 16 + lr] = lsum;
  }
}

// ---------------------------------------------------------------------------
// Merge partials for chunked groups (j >= 8). 768 blocks x 256 thr.
// thread -> (merged q-row, 4-wide d quad); out = sum(Opart)/sum(l).
// ---------------------------------------------------------------------------
__global__ __launch_bounds__(256) void merge_kernel(
    const float* __restrict__ Opart, const float* __restrict__ lpart,
    float* __restrict__ out)
{
  const int t = blockIdx.x * 256 + threadIdx.x;
  const int ridx = t >> 4;           // 0..12287
  const int dq = (t & 15) * 4;
  const int b = ridx / 1536;
  const int r2 = ridx % 1536;
  const int jj = r2 >> 6;            // 0..23 -> j = jj+8
  const int ql = r2 & 63;
  int pb, nch;
  if (jj < 8)       { pb = 2 * jj;            nch = 2; }
  else if (jj < 16) { pb = 16 + 3 * (jj - 8); nch = 3; }
  else              { pb = 40 + 4 * (jj - 16); nch = 4; }
  const int base = b * 72 + pb;
  f32x4 acc = {0.f, 0.f, 0.f, 0.f};
  float l = 0.f;
  for (int c = 0; c < nch; ++c) {
    acc += *(const f32x4*)(Opart + (((size_t)(base + c) * 64 + ql) * 64 + dq));
    l += lpart[(base + c) * 64 + ql];
  }
  const float inv = 1.0f / l;
  *(f32x4*)&out[((size_t)(b * 2048 + (jj + 8) * 64 + ql)) * 64 + dq] = acc * inv;
}

extern "C" void kernel_launch(void* const* d_in, const int* in_sizes, int n_in,
                              void* d_out, int out_size, void* d_ws, size_t ws_size,
                              hipStream_t stream) {
  // setup_inputs order: x, Wk, Wq, Wv
  const float* x  = (const float*)d_in[0];
  const float* Wk = (const float*)d_in[1];
  const float* Wq = (const float*)d_in[2];
  const float* Wv = (const float*)d_in[3];

  u16* wcat = (u16*)d_ws;                        // 192*1024       = 196608
  u16* qw   = wcat + 196608;                     // 16384*64
  u16* kw   = qw + 1048576;
  u16* vtw  = kw + 1048576;
  float* Opart = (float*)(vtw + 1048576);        // 576*64*64 f32
  float* lpart = Opart + 2359296;                // 576*64 f32
  float* out = (float*)d_out;

  wconv_kernel<<<dim3(96),  dim3(256), 0, stream>>>(Wk, Wq, Wv, wcat);
  proj_kernel <<<dim3(256), dim3(512), 0, stream>>>(x, wcat, qw, kw, vtw);
  attn_kernel <<<dim3(640), dim3(256), 0, stream>>>(qw, kw, vtw, out, Opart, lpart);
  merge_kernel<<<dim3(768), dim3(256), 0, stream>>>(Opart, lpart, out);
}

// Round 10
// 46.038 us; speedup vs baseline: 1.0785x; 1.0785x over previous
//
#include <hip/hip_runtime.h>

typedef short short8 __attribute__((ext_vector_type(8)));
typedef float f32x4 __attribute__((ext_vector_type(4)));
typedef unsigned int u32;
typedef unsigned short u16;

union PackU { u32 u[4]; short8 s8; };

__device__ __forceinline__ u16 f2bf(float f) {
  unsigned u = __builtin_bit_cast(unsigned, f);
  u = (u + 0x7FFFu + ((u >> 16) & 1u)) >> 16;
  return (u16)u;
}

__device__ __forceinline__ u32 cvt_pk_bf16(float lo, float hi) {
  u32 r;
  asm("v_cvt_pk_bf16_f32 %0, %1, %2" : "=v"(r) : "v"(lo), "v"(hi));
  return r;
}

__device__ __forceinline__ f32x4 mfma16(short8 a, short8 b, f32x4 c) {
  return __builtin_amdgcn_mfma_f32_16x16x32_bf16(a, b, c, 0, 0, 0);
}

// scale for Wq: (1/sqrt(1024)) * log2(e)  -> scores come out in log2 domain
#define QSCALE 0.04508422619125366f

// ---------------------------------------------------------------------------
// W conversion: wcat[192][1024] bf16 (plain layout). rows 0..63 = Wq*QSCALE,
// 64..127 = Wk, 128..191 = Wv.  grid 96 x 256, 8 elems/thread.
// ---------------------------------------------------------------------------
__global__ __launch_bounds__(256) void wconv_kernel(
    const float* __restrict__ Wk, const float* __restrict__ Wq,
    const float* __restrict__ Wv, u16* __restrict__ wcat)
{
  const int t = blockIdx.x * 256 + threadIdx.x;   // 24576 threads
  const int row = t >> 7;
  const int col = (t & 127) * 8;
  const float* src;
  float scale = 1.0f;
  if (row < 64)       { src = Wq + (size_t)row * 1024;        scale = QSCALE; }
  else if (row < 128) { src = Wk + (size_t)(row - 64) * 1024; }
  else                { src = Wv + (size_t)(row - 128) * 1024; }
  float4 a = *(const float4*)(src + col);
  float4 b = *(const float4*)(src + col + 4);
  PackU p;
  p.u[0] = cvt_pk_bf16(a.x * scale, a.y * scale);
  p.u[1] = cvt_pk_bf16(a.z * scale, a.w * scale);
  p.u[2] = cvt_pk_bf16(b.x * scale, b.y * scale);
  p.u[3] = cvt_pk_bf16(b.z * scale, b.w * scale);
  *(short8*)&wcat[(size_t)row * 1024 + col] = p.s8;
}

// ---------------------------------------------------------------------------
// Projection: 512 blocks x 256 thr (4 waves, 2 row x 2 col). hw block h:
// rt = h & 255 (64-token row tile), nh = h >> 8 (96-head half). Pairs
// (h, h+256) share the same x rows AND the same XCD (h%8 == (h+256)%8
// under round-robin dispatch) -> second x read hits L2/L3; two independent
// barrier domains per CU hide each other's load stalls.
// Depth-2 reg prefetch into double-buffered LDS (R5 structure): step s
// issues loads for s+2, commits regs of s+1 to LDS after MFMAs, one
// barrier per step. x converted f32->bf16 in-flight (cvt_pk). LDS 40KB.
// Outputs: qw,kw [8][2048][64] bf16; vtw [8][64][2048] bf16 in PERMUTED
// key order: token t stored at (t&~31)|((t>>2)&3)<<3|((t>>4)&1)<<2|(t&3).
// ---------------------------------------------------------------------------
struct Stage {
  float4 x0, x1, x2, x3;     // 16 fp32 of x (one 64B span)
  short8 w0, w1, w2;         // 3 row-chunks of W (wsr + 32i)
};

__global__ __launch_bounds__(256, 2) void proj_kernel(
    const float* __restrict__ x, const u16* __restrict__ wcat,
    u16* __restrict__ qw, u16* __restrict__ kw, u16* __restrict__ vtw)
{
  const int tid   = threadIdx.x;
  const int lane  = tid & 63;
  const int w     = tid >> 6;            // 4 waves
  const int lr    = lane & 15, lg = lane >> 4;
  const int wr    = w >> 1, wc = w & 1;  // 2x2 wave grid: 32 rows x 48 cols
  const int rt    = blockIdx.x & 255;
  const int nh    = blockIdx.x >> 8;     // 0 or 1
  const int row0  = rt * 64;
  const int ncol0 = nh * 96;

  __shared__ u16 lX[2][64 * 64];    // 2 x 8KB  bf16, XOR-swizzled
  __shared__ u16 lW[2][96 * 64];    // 2 x 12KB bf16, XOR-swizzled

  // staging geometry
  const int xr = tid >> 2;               // 0..63
  const int xc = (tid & 3) * 16;         // 0,16,32,48
  const float* xp = x + (size_t)(row0 + xr) * 1024 + xc;
  const int xIdx0 = xr * 64 + (xc ^ ((xr & 7) << 3));
  const int xIdx1 = xr * 64 + ((xc + 8) ^ ((xr & 7) << 3));
  const int wsr = tid >> 3;              // 0..31 (rows wsr + 32i, i=0..2)
  const int wsc = (tid & 7) * 8;
  const u16* wp = wcat + (size_t)(ncol0 + wsr) * 1024 + wsc;
  const int wIdx = wsr * 64 + (wsc ^ ((wsr & 7) << 3));   // (wsr+32i)&7 == wsr&7

  const f32x4 vzero = {0.f, 0.f, 0.f, 0.f};
  f32x4 acc[2][3];
#pragma unroll
  for (int m = 0; m < 2; ++m)
#pragma unroll
    for (int c = 0; c < 3; ++c) acc[m][c] = vzero;

  auto issue = [&](Stage& S, int k0) {
    S.x0 = *(const float4*)(xp + k0);
    S.x1 = *(const float4*)(xp + k0 + 4);
    S.x2 = *(const float4*)(xp + k0 + 8);
    S.x3 = *(const float4*)(xp + k0 + 12);
    S.w0 = *(const short8*)(wp + k0);
    S.w1 = *(const short8*)(wp + k0 + 32 * 1024);
    S.w2 = *(const short8*)(wp + k0 + 64 * 1024);
  };
  auto commit = [&](const Stage& S, int buf) {
    PackU p0, p1;
    p0.u[0] = cvt_pk_bf16(S.x0.x, S.x0.y);
    p0.u[1] = cvt_pk_bf16(S.x0.z, S.x0.w);
    p0.u[2] = cvt_pk_bf16(S.x1.x, S.x1.y);
    p0.u[3] = cvt_pk_bf16(S.x1.z, S.x1.w);
    p1.u[0] = cvt_pk_bf16(S.x2.x, S.x2.y);
    p1.u[1] = cvt_pk_bf16(S.x2.z, S.x2.w);
    p1.u[2] = cvt_pk_bf16(S.x3.x, S.x3.y);
    p1.u[3] = cvt_pk_bf16(S.x3.z, S.x3.w);
    *(short8*)&lX[buf][xIdx0]        = p0.s8;
    *(short8*)&lX[buf][xIdx1]        = p1.s8;
    *(short8*)&lW[buf][wIdx]         = S.w0;
    *(short8*)&lW[buf][wIdx + 2048]  = S.w1;
    *(short8*)&lW[buf][wIdx + 4096]  = S.w2;
  };
  auto computeStep = [&](int buf) {
    short8 af[2][2], wf[3][2];
#pragma unroll
    for (int m = 0; m < 2; ++m) {
      const int ar = wr * 32 + m * 16 + lr;
#pragma unroll
      for (int ks = 0; ks < 2; ++ks)
        af[m][ks] = *(const short8*)&lX[buf][ar * 64 + ((ks * 32 + lg * 8) ^ ((ar & 7) << 3))];
    }
#pragma unroll
    for (int c = 0; c < 3; ++c) {
      const int nr = wc * 48 + c * 16 + lr;   // 0..95
#pragma unroll
      for (int ks = 0; ks < 2; ++ks)
        wf[c][ks] = *(const short8*)&lW[buf][nr * 64 + ((ks * 32 + lg * 8) ^ ((nr & 7) << 3))];
    }
#pragma unroll
    for (int m = 0; m < 2; ++m)
#pragma unroll
      for (int c = 0; c < 3; ++c) {
        acc[m][c] = mfma16(af[m][0], wf[c][0], acc[m][c]);
        acc[m][c] = mfma16(af[m][1], wf[c][1], acc[m][c]);
      }
  };

  Stage A, B;
  issue(A, 0);
  issue(B, 64);
  commit(A, 0);
  __syncthreads();

  for (int it = 0; it < 8; ++it) {
    const int s = 2 * it;
    // ---- even step s: LDS buf0 holds s; regB holds s+1 ----
    if (it < 7) issue(A, (s + 2) * 64);
    __builtin_amdgcn_sched_barrier(0);
    computeStep(0);
    commit(B, 1);
    __syncthreads();
    // ---- odd step s+1: LDS buf1 holds s+1; regA holds s+2 ----
    if (it < 7) issue(B, (s + 3) * 64);
    __builtin_amdgcn_sched_barrier(0);
    computeStep(1);
    if (it < 7) {
      commit(A, 0);
    }
    __syncthreads();
  }

  const int bb = row0 >> 11;
  const int tb = row0 & 2047;
#pragma unroll
  for (int m = 0; m < 2; ++m) {
    const int tl0 = tb + wr * 32 + 16 * m + 4 * lg;
#pragma unroll
    for (int c = 0; c < 3; ++c) {
      const int n  = ncol0 + wc * 48 + c * 16 + lr;   // 0..191
      const int hd = n & 63;
      if (n < 128) {
        u16* dst = (n < 64) ? qw : kw;
#pragma unroll
        for (int r = 0; r < 4; ++r)
          dst[((size_t)(bb * 2048 + tl0 + r)) * 64 + hd] = f2bf(acc[m][c][r]);
      } else {
        const int posb = (tl0 & ~31) | (((tl0 >> 2) & 3) << 3) | (((tl0 >> 4) & 1) << 2);
        u32* dst = (u32*)&vtw[((size_t)(bb * 64 + hd)) * 2048 + posb];
        dst[0] = cvt_pk_bf16(acc[m][c][0], acc[m][c][1]);
        dst[1] = cvt_pk_bf16(acc[m][c][2], acc[m][c][3]);
      }
    }
  }
}

// ---------------------------------------------------------------------------
// Attention partials. grid = 8 batches x 80 (group,chunk) blocks, 256 thr.
// Block = q-group j (64 rows = 4 waves x 16-row strips), KV chunk of <=8
// 64-key tiles staged in LDS (dbuf, XOR-swizzled), shared by the 4 waves.
// Swapped QK (A=K, B=Q): lane holds S[key=16c+4lg+r][q=lr]. Static-max
// softmax: P = exp2(S) (Wq pre-scaled by log2e/32), per-lane scalar lsum.
// PV: A=V(perm layout), B=P packed lane-locally. Chunked groups write
// unnormalized partials; single-chunk groups (j<8) write out directly.
// ---------------------------------------------------------------------------
__global__ __launch_bounds__(256, 2) void attn_kernel(
    const u16* __restrict__ qw, const u16* __restrict__ kw,
    const u16* __restrict__ vtw, float* __restrict__ out,
    float* __restrict__ Opart, float* __restrict__ lpart)
{
  const int tid  = threadIdx.x;
  const int lane = tid & 63;
  const int sid  = tid >> 6;           // strip 0..3
  const int lr   = lane & 15, lg = lane >> 4;
  const int bid  = blockIdx.x;
  const int b    = bid / 80;
  const int g    = bid % 80;

  int j, ch, nch;
  if (g < 8)       { j = g;                ch = 0;          nch = 1; }
  else if (g < 24) { int u = g - 8;  j = 8  + (u >> 1); ch = u & 1;  nch = 2; }
  else if (g < 48) { int u = g - 24; j = 16 + u / 3;    ch = u % 3;  nch = 3; }
  else             { int u = g - 48; j = 24 + (u >> 2); ch = u & 3;  nch = 4; }
  const int kt0 = ch * 8;
  const int kt1 = (kt0 + 8 < j + 1) ? (kt0 + 8) : (j + 1);
  const int q0r = j * 64 + sid * 16;

  __shared__ u16 lK[2][64 * 64];
  __shared__ u16 lV[2][64 * 64];

  const size_t qoff = ((size_t)(b * 2048 + q0r + lr)) * 64 + lg * 8;
  const short8 qa = *(const short8*)(qw + qoff);
  const short8 qb = *(const short8*)(qw + qoff + 32);

  const f32x4 vzero = {0.f, 0.f, 0.f, 0.f};
  f32x4 o[4];
#pragma unroll
  for (int i = 0; i < 4; ++i) o[i] = vzero;
  float lsum = 0.f;

  // staging geometry: 512 chunks per matrix, 2 per thread
  const int sr0 = tid >> 3;            // 0..31 (i=1 adds 32)
  const int sc0 = (tid & 7) * 8;
  const int la0 = (sr0 * 64 + sc0) ^ ((sr0 & 7) << 3);

  short8 kst[2], vst[2];
  {
    const int kb = kt0 * 64;
#pragma unroll
    for (int i = 0; i < 2; ++i) {
      const int r = sr0 + i * 32;
      kst[i] = *(const short8*)(kw  + ((size_t)(b * 2048 + kb + r)) * 64 + sc0);
      vst[i] = *(const short8*)(vtw + ((size_t)(b * 64 + r)) * 2048 + kb + sc0);
    }
#pragma unroll
    for (int i = 0; i < 2; ++i) {
      *(short8*)&lK[0][la0 + i * 2048] = kst[i];
      *(short8*)&lV[0][la0 + i * 2048] = vst[i];
    }
  }
  __syncthreads();

  for (int kt = kt0; kt < kt1; ++kt) {
    const int cur = (kt - kt0) & 1;
    if (kt + 1 < kt1) {
      const int kb = (kt + 1) * 64;
#pragma unroll
      for (int i = 0; i < 2; ++i) {
        const int r = sr0 + i * 32;
        kst[i] = *(const short8*)(kw  + ((size_t)(b * 2048 + kb + r)) * 64 + sc0);
        vst[i] = *(const short8*)(vtw + ((size_t)(b * 64 + r)) * 2048 + kb + sc0);
      }
    }
    // QK^T (swapped): s4[c][r] = S[key = 64kt+16c+4lg+r][q = q0r+lr]
    f32x4 s4[4];
#pragma unroll
    for (int c = 0; c < 4; ++c) {
      const int row = 16 * c + lr;
      const short8 kf0 = *(const short8*)&lK[cur][(row * 64 + lg * 8) ^ ((row & 7) << 3)];
      const short8 kf1 = *(const short8*)&lK[cur][(row * 64 + 32 + lg * 8) ^ ((row & 7) << 3)];
      f32x4 z = vzero;
      z = mfma16(kf0, qa, z);
      z = mfma16(kf1, qb, z);
      s4[c] = z;
    }
    if (kt == j) {   // causal mask on the diagonal tile
#pragma unroll
      for (int c = 0; c < 4; ++c)
#pragma unroll
        for (int r = 0; r < 4; ++r)
          if (16 * c + 4 * lg + r > sid * 16 + lr) s4[c][r] = -1e30f;
    }
    // exp2 + lane-local row-sum accumulation
#pragma unroll
    for (int c = 0; c < 4; ++c)
#pragma unroll
      for (int r = 0; r < 4; ++r) {
        const float e = __builtin_amdgcn_exp2f(s4[c][r]);
        s4[c][r] = e;
        lsum += e;
      }
    // pack P lane-locally: pb0 = keys of c=0,1 ; pb1 = keys of c=2,3
    PackU p0, p1;
    p0.u[0] = cvt_pk_bf16(s4[0][0], s4[0][1]);
    p0.u[1] = cvt_pk_bf16(s4[0][2], s4[0][3]);
    p0.u[2] = cvt_pk_bf16(s4[1][0], s4[1][1]);
    p0.u[3] = cvt_pk_bf16(s4[1][2], s4[1][3]);
    p1.u[0] = cvt_pk_bf16(s4[2][0], s4[2][1]);
    p1.u[1] = cvt_pk_bf16(s4[2][2], s4[2][3]);
    p1.u[2] = cvt_pk_bf16(s4[3][0], s4[3][1]);
    p1.u[3] = cvt_pk_bf16(s4[3][2], s4[3][3]);
    const short8 pb0 = p0.s8, pb1 = p1.s8;
    // PV: o[cd] over d = 16cd+4lg+r
#pragma unroll
    for (int cd = 0; cd < 4; ++cd) {
      const int row = 16 * cd + lr;
      const short8 vf0 = *(const short8*)&lV[cur][(row * 64 + lg * 8) ^ ((row & 7) << 3)];
      const short8 vf1 = *(const short8*)&lV[cur][(row * 64 + 32 + lg * 8) ^ ((row & 7) << 3)];
      o[cd] = mfma16(vf0, pb0, o[cd]);
      o[cd] = mfma16(vf1, pb1, o[cd]);
    }
    if (kt + 1 < kt1) {
#pragma unroll
      for (int i = 0; i < 2; ++i) {
        *(short8*)&lK[cur ^ 1][la0 + i * 2048] = kst[i];
        *(short8*)&lV[cur ^ 1][la0 + i * 2048] = vst[i];
      }
      __syncthreads();
    }
  }

  lsum += __shfl_xor(lsum, 16, 64);
  lsum += __shfl_xor(lsum, 32, 64);

  if (nch == 1) {
    const float inv = 1.0f / lsum;
    float* op = out + ((size_t)(b * 2048 + q0r + lr)) * 64;
#pragma unroll
    for (int cd = 0; cd < 4; ++cd) {
      f32x4 v = o[cd] * inv;
      *(f32x4*)(op + 16 * cd + 4 * lg) = v;
    }
  } else {
    int pb;
    if (j < 16)      pb = 2 * (j - 8);
    else if (j < 24) pb = 16 + 3 * (j - 16);
    else             pb = 40 + 4 * (j - 24);
    const int pidx = b * 72 + pb + ch;
    float* op = Opart + ((size_t)(pidx * 64) + sid * 16 + lr) * 64;
#pragma unroll
    for (int cd = 0; cd < 4; ++cd)
      *(f32x4*)(op + 16 * cd + 4 * lg) = o[cd];
    if (lg == 0) lpart[pidx * 64 + sid * 16 + lr] = lsum;
  }
}

// ---------------------------------------------------------------------------
// Merge partials for chunked groups (j >= 8). 768 blocks x 256 thr.
// thread -> (merged q-row, 4-wide d quad); out = sum(Opart)/sum(l).
// ---------------------------------------------------------------------------
__global__ __launch_bounds__(256) void merge_kernel(
    const float* __restrict__ Opart, const float* __restrict__ lpart,
    float* __restrict__ out)
{
  const int t = blockIdx.x * 256 + threadIdx.x;
  const int ridx = t >> 4;           // 0..12287
  const int dq = (t & 15) * 4;
  const int b = ridx / 1536;
  const int r2 = ridx % 1536;
  const int jj = r2 >> 6;            // 0..23 -> j = jj+8
  const int ql = r2 & 63;
  int pb, nch;
  if (jj < 8)       { pb = 2 * jj;            nch = 2; }
  else if (jj < 16) { pb = 16 + 3 * (jj - 8); nch = 3; }
  else              { pb = 40 + 4 * (jj - 16); nch = 4; }
  const int base = b * 72 + pb;
  f32x4 acc = {0.f, 0.f, 0.f, 0.f};
  float l = 0.f;
  for (int c = 0; c < nch; ++c) {
    acc += *(const f32x4*)(Opart + (((size_t)(base + c) * 64 + ql) * 64 + dq));
    l += lpart[(base + c) * 64 + ql];
  }
  const float inv = 1.0f / l;
  *(f32x4*)&out[((size_t)(b * 2048 + (jj + 8) * 64 + ql)) * 64 + dq] = acc * inv;
}

extern "C" void kernel_launch(void* const* d_in, const int* in_sizes, int n_in,
                              void* d_out, int out_size, void* d_ws, size_t ws_size,
                              hipStream_t stream) {
  // setup_inputs order: x, Wk, Wq, Wv
  const float* x  = (const float*)d_in[0];
  const float* Wk = (const float*)d_in[1];
  const float* Wq = (const float*)d_in[2];
  const float* Wv = (const float*)d_in[3];

  u16* wcat = (u16*)d_ws;                        // 192*1024       = 196608
  u16* qw   = wcat + 196608;                     // 16384*64
  u16* kw   = qw + 1048576;
  u16* vtw  = kw + 1048576;
  float* Opart = (float*)(vtw + 1048576);        // 576*64*64 f32
  float* lpart = Opart + 2359296;                // 576*64 f32
  float* out = (float*)d_out;

  wconv_kernel<<<dim3(96),  dim3(256), 0, stream>>>(Wk, Wq, Wv, wcat);
  proj_kernel <<<dim3(512), dim3(256), 0, stream>>>(x, wcat, qw, kw, vtw);
  attn_kernel <<<dim3(640), dim3(256), 0, stream>>>(qw, kw, vtw, out, Opart, lpart);
  merge_kernel<<<dim3(768), dim3(256), 0, stream>>>(Opart, lpart, out);
}

// Round 11
// 43.339 us; speedup vs baseline: 1.1456x; 1.0623x over previous
//
#include <hip/hip_runtime.h>

typedef short short8 __attribute__((ext_vector_type(8)));
typedef float f32x4 __attribute__((ext_vector_type(4)));
typedef unsigned int u32;
typedef unsigned short u16;

union PackU { u32 u[4]; short8 s8; };

__device__ __forceinline__ u16 f2bf(float f) {
  unsigned u = __builtin_bit_cast(unsigned, f);
  u = (u + 0x7FFFu + ((u >> 16) & 1u)) >> 16;
  return (u16)u;
}

__device__ __forceinline__ u32 cvt_pk_bf16(float lo, float hi) {
  u32 r;
  asm("v_cvt_pk_bf16_f32 %0, %1, %2" : "=v"(r) : "v"(lo), "v"(hi));
  return r;
}

__device__ __forceinline__ f32x4 mfma16(short8 a, short8 b, f32x4 c) {
  return __builtin_amdgcn_mfma_f32_16x16x32_bf16(a, b, c, 0, 0, 0);
}

// scale for Wq: (1/sqrt(1024)) * log2(e)  -> scores come out in log2 domain
#define QSCALE 0.04508422619125366f

// ---------------------------------------------------------------------------
// W conversion: wcat[192][1024] bf16 (plain). rows 0..63 = Wq*QSCALE,
// 64..127 = Wk, 128..191 = Wv.  grid 96 x 256, 8 elems/thread.
// ---------------------------------------------------------------------------
__global__ __launch_bounds__(256) void wconv_kernel(
    const float* __restrict__ Wk, const float* __restrict__ Wq,
    const float* __restrict__ Wv, u16* __restrict__ wcat)
{
  const int t = blockIdx.x * 256 + threadIdx.x;   // 24576 threads
  const int row = t >> 7;
  const int col = (t & 127) * 8;
  const float* src;
  float scale = 1.0f;
  if (row < 64)       { src = Wq + (size_t)row * 1024;        scale = QSCALE; }
  else if (row < 128) { src = Wk + (size_t)(row - 64) * 1024; }
  else                { src = Wv + (size_t)(row - 128) * 1024; }
  float4 a = *(const float4*)(src + col);
  float4 b = *(const float4*)(src + col + 4);
  PackU p;
  p.u[0] = cvt_pk_bf16(a.x * scale, a.y * scale);
  p.u[1] = cvt_pk_bf16(a.z * scale, a.w * scale);
  p.u[2] = cvt_pk_bf16(b.x * scale, b.y * scale);
  p.u[3] = cvt_pk_bf16(b.z * scale, b.w * scale);
  *(short8*)&wcat[(size_t)row * 1024 + col] = p.s8;
}

// ---------------------------------------------------------------------------
// Projection (R5 structure, best measured): 256 blocks x 512 thr (8 waves,
// 2 row x 4 col). Block = 64 tokens x 192 heads. BK=64. x AND W staged
// through double-buffered LDS via registers; x converted f32->bf16
// in-flight (cvt_pk). Depth-2 prefetch: step s issues loads for s+2,
// commits regs of s+1 to LDS after MFMAs, one barrier per step.
// Outputs: qw,kw [8][2048][64] bf16; vtw [8][64][2048] bf16 in PERMUTED
// key order: token t stored at (t&~31)|((t>>2)&3)<<3|((t>>4)&1)<<2|(t&3).
// ---------------------------------------------------------------------------
struct Stage {
  float4 x0, x1;        // 8 fp32 of x
  short8 w0, w1, w2;    // 3 rows-chunks of W (r, r+64, r+128)
};

__global__ __launch_bounds__(512, 2) void proj_kernel(
    const float* __restrict__ x, const u16* __restrict__ wcat,
    u16* __restrict__ qw, u16* __restrict__ kw, u16* __restrict__ vtw)
{
  const int tid  = threadIdx.x;
  const int lane = tid & 63;
  const int w    = tid >> 6;
  const int lr   = lane & 15, lg = lane >> 4;
  const int wr   = w >> 2, wc = w & 3;   // 2x4 wave grid
  const int row0 = blockIdx.x * 64;

  __shared__ u16 lX[2][64 * 64];    // 2 x 8KB
  __shared__ u16 lW[2][192 * 64];   // 2 x 24KB

  // staging geometry: thread -> (row tid>>3, col (tid&7)*8)
  const int sr = tid >> 3;              // 0..63
  const int sc = (tid & 7) * 8;
  const float* xp = x    + (size_t)(row0 + sr) * 1024 + sc;
  const u16*   wp = wcat + (size_t)sr * 1024 + sc;
  const int sIdx = (sr * 64 + sc) ^ ((sr & 7) << 3);   // same swizzle all 3 W rows

  const f32x4 vzero = {0.f, 0.f, 0.f, 0.f};
  f32x4 acc[2][3];
#pragma unroll
  for (int m = 0; m < 2; ++m)
#pragma unroll
    for (int c = 0; c < 3; ++c) acc[m][c] = vzero;

  auto issue = [&](Stage& S, int k0) {
    S.x0 = *(const float4*)(xp + k0);
    S.x1 = *(const float4*)(xp + k0 + 4);
    S.w0 = *(const short8*)(wp + k0);
    S.w1 = *(const short8*)(wp + k0 + 65536);    // +64 rows
    S.w2 = *(const short8*)(wp + k0 + 131072);   // +128 rows
  };
  auto commit = [&](const Stage& S, int buf) {
    PackU p;
    p.u[0] = cvt_pk_bf16(S.x0.x, S.x0.y);
    p.u[1] = cvt_pk_bf16(S.x0.z, S.x0.w);
    p.u[2] = cvt_pk_bf16(S.x1.x, S.x1.y);
    p.u[3] = cvt_pk_bf16(S.x1.z, S.x1.w);
    *(short8*)&lX[buf][sIdx]        = p.s8;
    *(short8*)&lW[buf][sIdx]        = S.w0;
    *(short8*)&lW[buf][sIdx + 4096] = S.w1;
    *(short8*)&lW[buf][sIdx + 8192] = S.w2;
  };
  auto computeStep = [&](int buf) {
    short8 af[2][2], wf[3][2];
#pragma unroll
    for (int m = 0; m < 2; ++m) {
      const int ar = wr * 32 + m * 16 + lr;
#pragma unroll
      for (int ks = 0; ks < 2; ++ks)
        af[m][ks] = *(const short8*)&lX[buf][(ar * 64 + ks * 32 + lg * 8) ^ ((ar & 7) << 3)];
    }
#pragma unroll
    for (int c = 0; c < 3; ++c) {
      const int nr = wc * 48 + c * 16 + lr;
#pragma unroll
      for (int ks = 0; ks < 2; ++ks)
        wf[c][ks] = *(const short8*)&lW[buf][(nr * 64 + ks * 32 + lg * 8) ^ ((nr & 7) << 3)];
    }
#pragma unroll
    for (int m = 0; m < 2; ++m)
#pragma unroll
      for (int c = 0; c < 3; ++c) {
        acc[m][c] = mfma16(af[m][0], wf[c][0], acc[m][c]);
        acc[m][c] = mfma16(af[m][1], wf[c][1], acc[m][c]);
      }
  };

  Stage A, B;
  issue(A, 0);
  issue(B, 64);
  commit(A, 0);
  __syncthreads();

  for (int it = 0; it < 8; ++it) {
    const int s = 2 * it;
    // ---- even step s: LDS buf0 holds s; regB holds s+1 ----
    if (it < 7) issue(A, (s + 2) * 64);
    __builtin_amdgcn_sched_barrier(0);
    computeStep(0);
    commit(B, 1);
    __syncthreads();
    // ---- odd step s+1: LDS buf1 holds s+1; regA holds s+2 ----
    if (it < 7) issue(B, (s + 3) * 64);
    __builtin_amdgcn_sched_barrier(0);
    computeStep(1);
    if (it < 7) {
      commit(A, 0);
    }
    __syncthreads();
  }

  const int bb = row0 >> 11;
  const int tb = row0 & 2047;
#pragma unroll
  for (int m = 0; m < 2; ++m) {
    const int tl0 = tb + wr * 32 + 16 * m + 4 * lg;
#pragma unroll
    for (int c = 0; c < 3; ++c) {
      const int n  = wc * 48 + c * 16 + lr;
      const int hd = n & 63;
      if (n < 128) {
        u16* dst = (n < 64) ? qw : kw;
#pragma unroll
        for (int r = 0; r < 4; ++r)
          dst[((size_t)(bb * 2048 + tl0 + r)) * 64 + hd] = f2bf(acc[m][c][r]);
      } else {
        const int posb = (tl0 & ~31) | (((tl0 >> 2) & 3) << 3) | (((tl0 >> 4) & 1) << 2);
        u32* dst = (u32*)&vtw[((size_t)(bb * 64 + hd)) * 2048 + posb];
        dst[0] = cvt_pk_bf16(acc[m][c][0], acc[m][c][1]);
        dst[1] = cvt_pk_bf16(acc[m][c][2], acc[m][c][3]);
      }
    }
  }
}

// ---------------------------------------------------------------------------
// Attention partials. grid = 8 batches x 144 (group,chunk) blocks, 256 thr.
// Chunk = up to 4 KV tiles (256 keys) -> 4.5 blocks/CU for latency overlap.
// Tier t = j>>2: groups j=4t..4t+3 have nch=t+1 chunks; block offset within
// batch: 2t(t+1) + (j-4t)(t+1) + ch.  Block = q-group j (64 rows = 4 waves
// x 16-row strips); KV tiles staged in LDS (dbuf, XOR-swizzled).
// Swapped QK (A=K, B=Q): lane holds S[key=16c+4lg+r][q=lr]. Static-max
// softmax: P = exp2(S) (Wq pre-scaled by log2e/32), per-lane scalar lsum.
// PV: A=V(perm layout), B=P packed lane-locally. Chunked groups write
// unnormalized partials to slot b*144+g; tier-0 groups write out directly.
// ---------------------------------------------------------------------------
__global__ __launch_bounds__(256, 4) void attn_kernel(
    const u16* __restrict__ qw, const u16* __restrict__ kw,
    const u16* __restrict__ vtw, float* __restrict__ out,
    float* __restrict__ Opart, float* __restrict__ lpart)
{
  const int tid  = threadIdx.x;
  const int lane = tid & 63;
  const int sid  = tid >> 6;           // strip 0..3
  const int lr   = lane & 15, lg = lane >> 4;
  const int bid  = blockIdx.x;
  const int b    = bid / 144;
  const int g    = bid % 144;

  int t = 0;
  while (g >= 2 * (t + 1) * (t + 2)) ++t;        // tier 0..7
  const int u   = g - 2 * t * (t + 1);
  const int j   = 4 * t + u / (t + 1);
  const int ch  = u % (t + 1);
  const int kt0 = ch * 4;
  const int kt1 = (kt0 + 4 < j + 1) ? (kt0 + 4) : (j + 1);
  const int q0r = j * 64 + sid * 16;

  __shared__ u16 lK[2][64 * 64];
  __shared__ u16 lV[2][64 * 64];

  const size_t qoff = ((size_t)(b * 2048 + q0r + lr)) * 64 + lg * 8;
  const short8 qa = *(const short8*)(qw + qoff);
  const short8 qb = *(const short8*)(qw + qoff + 32);

  const f32x4 vzero = {0.f, 0.f, 0.f, 0.f};
  f32x4 o[4];
#pragma unroll
  for (int i = 0; i < 4; ++i) o[i] = vzero;
  float lsum = 0.f;

  // staging geometry: 512 chunks per matrix, 2 per thread
  const int sr0 = tid >> 3;            // 0..31 (i=1 adds 32)
  const int sc0 = (tid & 7) * 8;
  const int la0 = (sr0 * 64 + sc0) ^ ((sr0 & 7) << 3);

  short8 kst[2], vst[2];
  {
    const int kb = kt0 * 64;
#pragma unroll
    for (int i = 0; i < 2; ++i) {
      const int r = sr0 + i * 32;
      kst[i] = *(const short8*)(kw  + ((size_t)(b * 2048 + kb + r)) * 64 + sc0);
      vst[i] = *(const short8*)(vtw + ((size_t)(b * 64 + r)) * 2048 + kb + sc0);
    }
#pragma unroll
    for (int i = 0; i < 2; ++i) {
      *(short8*)&lK[0][la0 + i * 2048] = kst[i];
      *(short8*)&lV[0][la0 + i * 2048] = vst[i];
    }
  }
  __syncthreads();

  for (int kt = kt0; kt < kt1; ++kt) {
    const int cur = (kt - kt0) & 1;
    if (kt + 1 < kt1) {
      const int kb = (kt + 1) * 64;
#pragma unroll
      for (int i = 0; i < 2; ++i) {
        const int r = sr0 + i * 32;
        kst[i] = *(const short8*)(kw  + ((size_t)(b * 2048 + kb + r)) * 64 + sc0);
        vst[i] = *(const short8*)(vtw + ((size_t)(b * 64 + r)) * 2048 + kb + sc0);
      }
    }
    // QK^T (swapped): s4[c][r] = S[key = 64kt+16c+4lg+r][q = q0r+lr]
    f32x4 s4[4];
#pragma unroll
    for (int c = 0; c < 4; ++c) {
      const int row = 16 * c + lr;
      const short8 kf0 = *(const short8*)&lK[cur][(row * 64 + lg * 8) ^ ((row & 7) << 3)];
      const short8 kf1 = *(const short8*)&lK[cur][(row * 64 + 32 + lg * 8) ^ ((row & 7) << 3)];
      f32x4 z = vzero;
      z = mfma16(kf0, qa, z);
      z = mfma16(kf1, qb, z);
      s4[c] = z;
    }
    if (kt == j) {   // causal mask on the diagonal tile
#pragma unroll
      for (int c = 0; c < 4; ++c)
#pragma unroll
        for (int r = 0; r < 4; ++r)
          if (16 * c + 4 * lg + r > sid * 16 + lr) s4[c][r] = -1e30f;
    }
    // exp2 + lane-local row-sum accumulation
#pragma unroll
    for (int c = 0; c < 4; ++c)
#pragma unroll
      for (int r = 0; r < 4; ++r) {
        const float e = __builtin_amdgcn_exp2f(s4[c][r]);
        s4[c][r] = e;
        lsum += e;
      }
    // pack P lane-locally: pb0 = keys of c=0,1 ; pb1 = keys of c=2,3
    PackU p0, p1;
    p0.u[0] = cvt_pk_bf16(s4[0][0], s4[0][1]);
    p0.u[1] = cvt_pk_bf16(s4[0][2], s4[0][3]);
    p0.u[2] = cvt_pk_bf16(s4[1][0], s4[1][1]);
    p0.u[3] = cvt_pk_bf16(s4[1][2], s4[1][3]);
    p1.u[0] = cvt_pk_bf16(s4[2][0], s4[2][1]);
    p1.u[1] = cvt_pk_bf16(s4[2][2], s4[2][3]);
    p1.u[2] = cvt_pk_bf16(s4[3][0], s4[3][1]);
    p1.u[3] = cvt_pk_bf16(s4[3][2], s4[3][3]);
    const short8 pb0 = p0.s8, pb1 = p1.s8;
    // PV: o[cd] over d = 16cd+4lg+r
#pragma unroll
    for (int cd = 0; cd < 4; ++cd) {
      const int row = 16 * cd + lr;
      const short8 vf0 = *(const short8*)&lV[cur][(row * 64 + lg * 8) ^ ((row & 7) << 3)];
      const short8 vf1 = *(const short8*)&lV[cur][(row * 64 + 32 + lg * 8) ^ ((row & 7) << 3)];
      o[cd] = mfma16(vf0, pb0, o[cd]);
      o[cd] = mfma16(vf1, pb1, o[cd]);
    }
    if (kt + 1 < kt1) {
#pragma unroll
      for (int i = 0; i < 2; ++i) {
        *(short8*)&lK[cur ^ 1][la0 + i * 2048] = kst[i];
        *(short8*)&lV[cur ^ 1][la0 + i * 2048] = vst[i];
      }
      __syncthreads();
    }
  }

  lsum += __shfl_xor(lsum, 16, 64);
  lsum += __shfl_xor(lsum, 32, 64);

  if (t == 0) {
    const float inv = 1.0f / lsum;
    float* op = out + ((size_t)(b * 2048 + q0r + lr)) * 64;
#pragma unroll
    for (int cd = 0; cd < 4; ++cd) {
      f32x4 v = o[cd] * inv;
      *(f32x4*)(op + 16 * cd + 4 * lg) = v;
    }
  } else {
    const int pidx = b * 144 + g;
    float* op = Opart + ((size_t)(pidx * 64) + sid * 16 + lr) * 64;
#pragma unroll
    for (int cd = 0; cd < 4; ++cd)
      *(f32x4*)(op + 16 * cd + 4 * lg) = o[cd];
    if (lg == 0) lpart[pidx * 64 + sid * 16 + lr] = lsum;
  }
}

// ---------------------------------------------------------------------------
// Merge partials for chunked groups (j >= 4). 896 blocks x 256 thr.
// thread -> (merged q-row, 4-wide d quad); out = sum(Opart)/sum(l).
// ---------------------------------------------------------------------------
__global__ __launch_bounds__(256) void merge_kernel(
    const float* __restrict__ Opart, const float* __restrict__ lpart,
    float* __restrict__ out)
{
  const int t = blockIdx.x * 256 + threadIdx.x;
  const int ridx = t >> 4;           // 0..14335
  const int dq = (t & 15) * 4;
  const int b = ridx / 1792;         // 28 groups x 64 rows
  const int r2 = ridx % 1792;
  const int jj = 4 + (r2 >> 6);      // 4..31
  const int ql = r2 & 63;
  const int tt = jj >> 2;            // tier 1..7
  const int gstart = 2 * tt * (tt + 1) + (jj - 4 * tt) * (tt + 1);
  const int nch = tt + 1;
  const int base = b * 144 + gstart;
  f32x4 acc = {0.f, 0.f, 0.f, 0.f};
  float l = 0.f;
  for (int c = 0; c < nch; ++c) {
    acc += *(const f32x4*)(Opart + (((size_t)(base + c) * 64 + ql) * 64 + dq));
    l += lpart[(base + c) * 64 + ql];
  }
  const float inv = 1.0f / l;
  *(f32x4*)&out[((size_t)(b * 2048 + jj * 64 + ql)) * 64 + dq] = acc * inv;
}

extern "C" void kernel_launch(void* const* d_in, const int* in_sizes, int n_in,
                              void* d_out, int out_size, void* d_ws, size_t ws_size,
                              hipStream_t stream) {
  // setup_inputs order: x, Wk, Wq, Wv
  const float* x  = (const float*)d_in[0];
  const float* Wk = (const float*)d_in[1];
  const float* Wq = (const float*)d_in[2];
  const float* Wv = (const float*)d_in[3];

  u16* wcat = (u16*)d_ws;                        // 192*1024       = 196608
  u16* qw   = wcat + 196608;                     // 16384*64
  u16* kw   = qw + 1048576;
  u16* vtw  = kw + 1048576;
  float* Opart = (float*)(vtw + 1048576);        // 1152*64*64 f32 = 18.9 MB
  float* lpart = Opart + (size_t)1152 * 64 * 64; // 1152*64 f32
  float* out = (float*)d_out;

  wconv_kernel<<<dim3(96),  dim3(256), 0, stream>>>(Wk, Wq, Wv, wcat);
  proj_kernel <<<dim3(256), dim3(512), 0, stream>>>(x, wcat, qw, kw, vtw);
  attn_kernel <<<dim3(1152), dim3(256), 0, stream>>>(qw, kw, vtw, out, Opart, lpart);
  merge_kernel<<<dim3(896), dim3(256), 0, stream>>>(Opart, lpart, out);
}

// Round 12
// 43.075 us; speedup vs baseline: 1.1527x; 1.0061x over previous
//
#include <hip/hip_runtime.h>

typedef short short8 __attribute__((ext_vector_type(8)));
typedef float f32x4 __attribute__((ext_vector_type(4)));
typedef unsigned int u32;
typedef unsigned short u16;

union PackU { u32 u[4]; short8 s8; };

__device__ __forceinline__ u16 f2bf(float f) {
  unsigned u = __builtin_bit_cast(unsigned, f);
  u = (u + 0x7FFFu + ((u >> 16) & 1u)) >> 16;
  return (u16)u;
}

__device__ __forceinline__ u32 cvt_pk_bf16(float lo, float hi) {
  u32 r;
  asm("v_cvt_pk_bf16_f32 %0, %1, %2" : "=v"(r) : "v"(lo), "v"(hi));
  return r;
}

__device__ __forceinline__ f32x4 mfma16(short8 a, short8 b, f32x4 c) {
  return __builtin_amdgcn_mfma_f32_16x16x32_bf16(a, b, c, 0, 0, 0);
}

// scale for Wq: (1/sqrt(1024)) * log2(e)  -> scores come out in log2 domain
#define QSCALE 0.04508422619125366f

// ---------------------------------------------------------------------------
// W conversion: wcat[192][1024] bf16 (plain). rows 0..63 = Wq*QSCALE,
// 64..127 = Wk, 128..191 = Wv.  grid 96 x 256, 8 elems/thread.
// ---------------------------------------------------------------------------
__global__ __launch_bounds__(256) void wconv_kernel(
    const float* __restrict__ Wk, const float* __restrict__ Wq,
    const float* __restrict__ Wv, u16* __restrict__ wcat)
{
  const int t = blockIdx.x * 256 + threadIdx.x;   // 24576 threads
  const int row = t >> 7;
  const int col = (t & 127) * 8;
  const float* src;
  float scale = 1.0f;
  if (row < 64)       { src = Wq + (size_t)row * 1024;        scale = QSCALE; }
  else if (row < 128) { src = Wk + (size_t)(row - 64) * 1024; }
  else                { src = Wv + (size_t)(row - 128) * 1024; }
  float4 a = *(const float4*)(src + col);
  float4 b = *(const float4*)(src + col + 4);
  PackU p;
  p.u[0] = cvt_pk_bf16(a.x * scale, a.y * scale);
  p.u[1] = cvt_pk_bf16(a.z * scale, a.w * scale);
  p.u[2] = cvt_pk_bf16(b.x * scale, b.y * scale);
  p.u[3] = cvt_pk_bf16(b.z * scale, b.w * scale);
  *(short8*)&wcat[(size_t)row * 1024 + col] = p.s8;
}

// ---------------------------------------------------------------------------
// Projection: 256 blocks x 512 thr (8 waves, 2 row x 4 col). Block = 64
// tokens x 192 heads. BK=128 (8 steps -> half the barriers of R5's BK=64).
// x AND W staged through double-buffered LDS via registers; x converted
// f32->bf16 in-flight (cvt_pk). Depth-2 prefetch: step s issues loads for
// s+2, commits regs of s+1 to LDS after MFMAs, one barrier per step.
// LDS 2 x (16KB x + 48KB W) = 128 KB, 1 block/CU.
// Outputs: qw,kw [8][2048][64] bf16; vtw [8][64][2048] bf16 in PERMUTED
// key order: token t stored at (t&~31)|((t>>2)&3)<<3|((t>>4)&1)<<2|(t&3).
// ---------------------------------------------------------------------------
struct Stage {
  float4 x0, x1, x2, x3;          // 16 fp32 of x (one 64B span)
  short8 w0, w1, w2, w3, w4, w5;  // 6 chunks of W: rows {r,r+64,r+128} x col-halves {0,64}
};

__global__ __launch_bounds__(512, 2) void proj_kernel(
    const float* __restrict__ x, const u16* __restrict__ wcat,
    u16* __restrict__ qw, u16* __restrict__ kw, u16* __restrict__ vtw)
{
  const int tid  = threadIdx.x;
  const int lane = tid & 63;
  const int w    = tid >> 6;
  const int lr   = lane & 15, lg = lane >> 4;
  const int wr   = w >> 2, wc = w & 3;   // 2x4 wave grid
  const int row0 = blockIdx.x * 64;

  __shared__ u16 lX[2][64 * 128];    // 2 x 16KB
  __shared__ u16 lW[2][192 * 128];   // 2 x 48KB

  // staging geometry
  const int sr = tid >> 3;              // 0..63
  const int sc = (tid & 7) * 16;        // 0..112 (x), (tid&7)*8 for W
  const float* xp = x + (size_t)(row0 + sr) * 1024 + sc;
  const int xsw   = (sr & 7) << 3;
  const int xIdx0 = sr * 128 + (sc ^ xsw);
  const int xIdx1 = sr * 128 + ((sc + 8) ^ xsw);
  const int wcl = (tid & 7) * 8;        // 0..56
  const u16* wp = wcat + (size_t)sr * 1024 + wcl;
  const int wIdx = sr * 128 + (wcl ^ xsw);   // rows sr+64i share (sr&7)

  const f32x4 vzero = {0.f, 0.f, 0.f, 0.f};
  f32x4 acc[2][3];
#pragma unroll
  for (int m = 0; m < 2; ++m)
#pragma unroll
    for (int c = 0; c < 3; ++c) acc[m][c] = vzero;

  auto issue = [&](Stage& S, int k0) {
    S.x0 = *(const float4*)(xp + k0);
    S.x1 = *(const float4*)(xp + k0 + 4);
    S.x2 = *(const float4*)(xp + k0 + 8);
    S.x3 = *(const float4*)(xp + k0 + 12);
    S.w0 = *(const short8*)(wp + k0);
    S.w1 = *(const short8*)(wp + k0 + 64);
    S.w2 = *(const short8*)(wp + k0 + 65536);
    S.w3 = *(const short8*)(wp + k0 + 65600);
    S.w4 = *(const short8*)(wp + k0 + 131072);
    S.w5 = *(const short8*)(wp + k0 + 131136);
  };
  auto commit = [&](const Stage& S, int buf) {
    PackU p0, p1;
    p0.u[0] = cvt_pk_bf16(S.x0.x, S.x0.y);
    p0.u[1] = cvt_pk_bf16(S.x0.z, S.x0.w);
    p0.u[2] = cvt_pk_bf16(S.x1.x, S.x1.y);
    p0.u[3] = cvt_pk_bf16(S.x1.z, S.x1.w);
    p1.u[0] = cvt_pk_bf16(S.x2.x, S.x2.y);
    p1.u[1] = cvt_pk_bf16(S.x2.z, S.x2.w);
    p1.u[2] = cvt_pk_bf16(S.x3.x, S.x3.y);
    p1.u[3] = cvt_pk_bf16(S.x3.z, S.x3.w);
    *(short8*)&lX[buf][xIdx0]          = p0.s8;
    *(short8*)&lX[buf][xIdx1]          = p1.s8;
    *(short8*)&lW[buf][wIdx]           = S.w0;
    *(short8*)&lW[buf][wIdx + 64]      = S.w1;
    *(short8*)&lW[buf][wIdx + 8192]    = S.w2;
    *(short8*)&lW[buf][wIdx + 8256]    = S.w3;
    *(short8*)&lW[buf][wIdx + 16384]   = S.w4;
    *(short8*)&lW[buf][wIdx + 16448]   = S.w5;
  };
  auto computeStep = [&](int buf) {
    short8 af[2][4], wf[3][4];
#pragma unroll
    for (int m = 0; m < 2; ++m) {
      const int ar = wr * 32 + m * 16 + lr;
      const int v  = (ar & 7) << 3;
#pragma unroll
      for (int ks = 0; ks < 4; ++ks)
        af[m][ks] = *(const short8*)&lX[buf][ar * 128 + ((ks * 32 + lg * 8) ^ v)];
    }
#pragma unroll
    for (int c = 0; c < 3; ++c) {
      const int nr = wc * 48 + c * 16 + lr;
      const int v  = (nr & 7) << 3;
#pragma unroll
      for (int ks = 0; ks < 4; ++ks)
        wf[c][ks] = *(const short8*)&lW[buf][nr * 128 + ((ks * 32 + lg * 8) ^ v)];
    }
#pragma unroll
    for (int m = 0; m < 2; ++m)
#pragma unroll
      for (int c = 0; c < 3; ++c)
#pragma unroll
        for (int ks = 0; ks < 4; ++ks)
          acc[m][c] = mfma16(af[m][ks], wf[c][ks], acc[m][c]);
  };

  Stage A, B;
  issue(A, 0);
  issue(B, 128);
  commit(A, 0);
  __syncthreads();

  for (int it = 0; it < 4; ++it) {
    const int s = 2 * it;
    // ---- even step s: LDS buf0 holds s; regB holds s+1 ----
    if (it < 3) issue(A, (s + 2) * 128);
    __builtin_amdgcn_sched_barrier(0);
    computeStep(0);
    commit(B, 1);
    __syncthreads();
    // ---- odd step s+1: LDS buf1 holds s+1; regA holds s+2 ----
    if (it < 3) issue(B, (s + 3) * 128);
    __builtin_amdgcn_sched_barrier(0);
    computeStep(1);
    if (it < 3) {
      commit(A, 0);
    }
    __syncthreads();
  }

  const int bb = row0 >> 11;
  const int tb = row0 & 2047;
#pragma unroll
  for (int m = 0; m < 2; ++m) {
    const int tl0 = tb + wr * 32 + 16 * m + 4 * lg;
#pragma unroll
    for (int c = 0; c < 3; ++c) {
      const int n  = wc * 48 + c * 16 + lr;
      const int hd = n & 63;
      if (n < 128) {
        u16* dst = (n < 64) ? qw : kw;
#pragma unroll
        for (int r = 0; r < 4; ++r)
          dst[((size_t)(bb * 2048 + tl0 + r)) * 64 + hd] = f2bf(acc[m][c][r]);
      } else {
        const int posb = (tl0 & ~31) | (((tl0 >> 2) & 3) << 3) | (((tl0 >> 4) & 1) << 2);
        u32* dst = (u32*)&vtw[((size_t)(bb * 64 + hd)) * 2048 + posb];
        dst[0] = cvt_pk_bf16(acc[m][c][0], acc[m][c][1]);
        dst[1] = cvt_pk_bf16(acc[m][c][2], acc[m][c][3]);
      }
    }
  }
}

// ---------------------------------------------------------------------------
// Attention partials (R5 config). grid = 8 batches x 80 blocks, 256 thr.
// Block = q-group j (64 rows = 4 waves x 16-row strips), KV chunk of <=8
// 64-key tiles staged in LDS (dbuf, XOR-swizzled), shared by the 4 waves.
// Swapped QK (A=K, B=Q): lane holds S[key=16c+4lg+r][q=lr]. Static-max
// softmax: P = exp2(S) (Wq pre-scaled by log2e/32), per-lane scalar lsum.
// PV: A=V(perm layout), B=P packed lane-locally. Chunked groups write
// unnormalized partials; single-chunk groups (j<8) write out directly.
// ---------------------------------------------------------------------------
__global__ __launch_bounds__(256, 2) void attn_kernel(
    const u16* __restrict__ qw, const u16* __restrict__ kw,
    const u16* __restrict__ vtw, float* __restrict__ out,
    float* __restrict__ Opart, float* __restrict__ lpart)
{
  const int tid  = threadIdx.x;
  const int lane = tid & 63;
  const int sid  = tid >> 6;           // strip 0..3
  const int lr   = lane & 15, lg = lane >> 4;
  const int bid  = blockIdx.x;
  const int b    = bid / 80;
  const int g    = bid % 80;

  int j, ch, nch;
  if (g < 8)       { j = g;                ch = 0;          nch = 1; }
  else if (g < 24) { int u = g - 8;  j = 8  + (u >> 1); ch = u & 1;  nch = 2; }
  else if (g < 48) { int u = g - 24; j = 16 + u / 3;    ch = u % 3;  nch = 3; }
  else             { int u = g - 48; j = 24 + (u >> 2); ch = u & 3;  nch = 4; }
  const int kt0 = ch * 8;
  const int kt1 = (kt0 + 8 < j + 1) ? (kt0 + 8) : (j + 1);
  const int q0r = j * 64 + sid * 16;

  __shared__ u16 lK[2][64 * 64];
  __shared__ u16 lV[2][64 * 64];

  const size_t qoff = ((size_t)(b * 2048 + q0r + lr)) * 64 + lg * 8;
  const short8 qa = *(const short8*)(qw + qoff);
  const short8 qb = *(const short8*)(qw + qoff + 32);

  const f32x4 vzero = {0.f, 0.f, 0.f, 0.f};
  f32x4 o[4];
#pragma unroll
  for (int i = 0; i < 4; ++i) o[i] = vzero;
  float lsum = 0.f;

  // staging geometry: 512 chunks per matrix, 2 per thread
  const int sr0 = tid >> 3;            // 0..31 (i=1 adds 32)
  const int sc0 = (tid & 7) * 8;
  const int la0 = (sr0 * 64 + sc0) ^ ((sr0 & 7) << 3);

  short8 kst[2], vst[2];
  {
    const int kb = kt0 * 64;
#pragma unroll
    for (int i = 0; i < 2; ++i) {
      const int r = sr0 + i * 32;
      kst[i] = *(const short8*)(kw  + ((size_t)(b * 2048 + kb + r)) * 64 + sc0);
      vst[i] = *(const short8*)(vtw + ((size_t)(b * 64 + r)) * 2048 + kb + sc0);
    }
#pragma unroll
    for (int i = 0; i < 2; ++i) {
      *(short8*)&lK[0][la0 + i * 2048] = kst[i];
      *(short8*)&lV[0][la0 + i * 2048] = vst[i];
    }
  }
  __syncthreads();

  for (int kt = kt0; kt < kt1; ++kt) {
    const int cur = (kt - kt0) & 1;
    if (kt + 1 < kt1) {
      const int kb = (kt + 1) * 64;
#pragma unroll
      for (int i = 0; i < 2; ++i) {
        const int r = sr0 + i * 32;
        kst[i] = *(const short8*)(kw  + ((size_t)(b * 2048 + kb + r)) * 64 + sc0);
        vst[i] = *(const short8*)(vtw + ((size_t)(b * 64 + r)) * 2048 + kb + sc0);
      }
    }
    // QK^T (swapped): s4[c][r] = S[key = 64kt+16c+4lg+r][q = q0r+lr]
    f32x4 s4[4];
#pragma unroll
    for (int c = 0; c < 4; ++c) {
      const int row = 16 * c + lr;
      const short8 kf0 = *(const short8*)&lK[cur][(row * 64 + lg * 8) ^ ((row & 7) << 3)];
      const short8 kf1 = *(const short8*)&lK[cur][(row * 64 + 32 + lg * 8) ^ ((row & 7) << 3)];
      f32x4 z = vzero;
      z = mfma16(kf0, qa, z);
      z = mfma16(kf1, qb, z);
      s4[c] = z;
    }
    if (kt == j) {   // causal mask on the diagonal tile
#pragma unroll
      for (int c = 0; c < 4; ++c)
#pragma unroll
        for (int r = 0; r < 4; ++r)
          if (16 * c + 4 * lg + r > sid * 16 + lr) s4[c][r] = -1e30f;
    }
    // exp2 + lane-local row-sum accumulation
#pragma unroll
    for (int c = 0; c < 4; ++c)
#pragma unroll
      for (int r = 0; r < 4; ++r) {
        const float e = __builtin_amdgcn_exp2f(s4[c][r]);
        s4[c][r] = e;
        lsum += e;
      }
    // pack P lane-locally: pb0 = keys of c=0,1 ; pb1 = keys of c=2,3
    PackU p0, p1;
    p0.u[0] = cvt_pk_bf16(s4[0][0], s4[0][1]);
    p0.u[1] = cvt_pk_bf16(s4[0][2], s4[0][3]);
    p0.u[2] = cvt_pk_bf16(s4[1][0], s4[1][1]);
    p0.u[3] = cvt_pk_bf16(s4[1][2], s4[1][3]);
    p1.u[0] = cvt_pk_bf16(s4[2][0], s4[2][1]);
    p1.u[1] = cvt_pk_bf16(s4[2][2], s4[2][3]);
    p1.u[2] = cvt_pk_bf16(s4[3][0], s4[3][1]);
    p1.u[3] = cvt_pk_bf16(s4[3][2], s4[3][3]);
    const short8 pb0 = p0.s8, pb1 = p1.s8;
    // PV: o[cd] over d = 16cd+4lg+r
#pragma unroll
    for (int cd = 0; cd < 4; ++cd) {
      const int row = 16 * cd + lr;
      const short8 vf0 = *(const short8*)&lV[cur][(row * 64 + lg * 8) ^ ((row & 7) << 3)];
      const short8 vf1 = *(const short8*)&lV[cur][(row * 64 + 32 + lg * 8) ^ ((row & 7) << 3)];
      o[cd] = mfma16(vf0, pb0, o[cd]);
      o[cd] = mfma16(vf1, pb1, o[cd]);
    }
    if (kt + 1 < kt1) {
#pragma unroll
      for (int i = 0; i < 2; ++i) {
        *(short8*)&lK[cur ^ 1][la0 + i * 2048] = kst[i];
        *(short8*)&lV[cur ^ 1][la0 + i * 2048] = vst[i];
      }
      __syncthreads();
    }
  }

  lsum += __shfl_xor(lsum, 16, 64);
  lsum += __shfl_xor(lsum, 32, 64);

  if (nch == 1) {
    const float inv = 1.0f / lsum;
    float* op = out + ((size_t)(b * 2048 + q0r + lr)) * 64;
#pragma unroll
    for (int cd = 0; cd < 4; ++cd) {
      f32x4 v = o[cd] * inv;
      *(f32x4*)(op + 16 * cd + 4 * lg) = v;
    }
  } else {
    int pb;
    if (j < 16)      pb = 2 * (j - 8);
    else if (j < 24) pb = 16 + 3 * (j - 16);
    else             pb = 40 + 4 * (j - 24);
    const int pidx = b * 72 + pb + ch;
    float* op = Opart + ((size_t)(pidx * 64) + sid * 16 + lr) * 64;
#pragma unroll
    for (int cd = 0; cd < 4; ++cd)
      *(f32x4*)(op + 16 * cd + 4 * lg) = o[cd];
    if (lg == 0) lpart[pidx * 64 + sid * 16 + lr] = lsum;
  }
}

// ---------------------------------------------------------------------------
// Merge partials for chunked groups (j >= 8). 768 blocks x 256 thr.
// thread -> (merged q-row, 4-wide d quad); out = sum(Opart)/sum(l).
// ---------------------------------------------------------------------------
__global__ __launch_bounds__(256) void merge_kernel(
    const float* __restrict__ Opart, const float* __restrict__ lpart,
    float* __restrict__ out)
{
  const int t = blockIdx.x * 256 + threadIdx.x;
  const int ridx = t >> 4;           // 0..12287
  const int dq = (t & 15) * 4;
  const int b = ridx / 1536;
  const int r2 = ridx % 1536;
  const int jj = r2 >> 6;            // 0..23 -> j = jj+8
  const int ql = r2 & 63;
  int pb, nch;
  if (jj < 8)       { pb = 2 * jj;            nch = 2; }
  else if (jj < 16) { pb = 16 + 3 * (jj - 8); nch = 3; }
  else              { pb = 40 + 4 * (jj - 16); nch = 4; }
  const int base = b * 72 + pb;
  f32x4 acc = {0.f, 0.f, 0.f, 0.f};
  float l = 0.f;
  for (int c = 0; c < nch; ++c) {
    acc += *(const f32x4*)(Opart + (((size_t)(base + c) * 64 + ql) * 64 + dq));
    l += lpart[(base + c) * 64 + ql];
  }
  const float inv = 1.0f / l;
  *(f32x4*)&out[((size_t)(b * 2048 + (jj + 8) * 64 + ql)) * 64 + dq] = acc * inv;
}

extern "C" void kernel_launch(void* const* d_in, const int* in_sizes, int n_in,
                              void* d_out, int out_size, void* d_ws, size_t ws_size,
                              hipStream_t stream) {
  // setup_inputs order: x, Wk, Wq, Wv
  const float* x  = (const float*)d_in[0];
  const float* Wk = (const float*)d_in[1];
  const float* Wq = (const float*)d_in[2];
  const float* Wv = (const float*)d_in[3];

  u16* wcat = (u16*)d_ws;                        // 192*1024       = 196608
  u16* qw   = wcat + 196608;                     // 16384*64
  u16* kw   = qw + 1048576;
  u16* vtw  = kw + 1048576;
  float* Opart = (float*)(vtw + 1048576);        // 576*64*64 f32
  float* lpart = Opart + 2359296;                // 576*64 f32
  float* out = (float*)d_out;

  wconv_kernel<<<dim3(96),  dim3(256), 0, stream>>>(Wk, Wq, Wv, wcat);
  proj_kernel <<<dim3(256), dim3(512), 0, stream>>>(x, wcat, qw, kw, vtw);
  attn_kernel <<<dim3(640), dim3(256), 0, stream>>>(qw, kw, vtw, out, Opart, lpart);
  merge_kernel<<<dim3(768), dim3(256), 0, stream>>>(Opart, lpart, out);
}

// Round 14
// 41.027 us; speedup vs baseline: 1.2102x; 1.0499x over previous
//
#include <hip/hip_runtime.h>

typedef short short8 __attribute__((ext_vector_type(8)));
typedef float f32x4 __attribute__((ext_vector_type(4)));
typedef unsigned int u32;
typedef unsigned short u16;

union PackU { u32 u[4]; short8 s8; };

__device__ __forceinline__ u16 f2bf(float f) {
  unsigned u = __builtin_bit_cast(unsigned, f);
  u = (u + 0x7FFFu + ((u >> 16) & 1u)) >> 16;
  return (u16)u;
}

__device__ __forceinline__ u32 cvt_pk_bf16(float lo, float hi) {
  u32 r;
  asm("v_cvt_pk_bf16_f32 %0, %1, %2" : "=v"(r) : "v"(lo), "v"(hi));
  return r;
}

__device__ __forceinline__ f32x4 mfma16(short8 a, short8 b, f32x4 c) {
  return __builtin_amdgcn_mfma_f32_16x16x32_bf16(a, b, c, 0, 0, 0);
}

// scale for Wq: (1/sqrt(1024)) * log2(e)  -> scores come out in log2 domain
#define QSCALE 0.04508422619125366f

// ---------------------------------------------------------------------------
// W conversion: wcat[192][1024] bf16 (plain). rows 0..63 = Wq*QSCALE,
// 64..127 = Wk, 128..191 = Wv.  grid 96 x 256, 8 elems/thread.
// ---------------------------------------------------------------------------
__global__ __launch_bounds__(256) void wconv_kernel(
    const float* __restrict__ Wk, const float* __restrict__ Wq,
    const float* __restrict__ Wv, u16* __restrict__ wcat)
{
  const int t = blockIdx.x * 256 + threadIdx.x;   // 24576 threads
  const int row = t >> 7;
  const int col = (t & 127) * 8;
  const float* src;
  float scale = 1.0f;
  if (row < 64)       { src = Wq + (size_t)row * 1024;        scale = QSCALE; }
  else if (row < 128) { src = Wk + (size_t)(row - 64) * 1024; }
  else                { src = Wv + (size_t)(row - 128) * 1024; }
  float4 a = *(const float4*)(src + col);
  float4 b = *(const float4*)(src + col + 4);
  PackU p;
  p.u[0] = cvt_pk_bf16(a.x * scale, a.y * scale);
  p.u[1] = cvt_pk_bf16(a.z * scale, a.w * scale);
  p.u[2] = cvt_pk_bf16(b.x * scale, b.y * scale);
  p.u[3] = cvt_pk_bf16(b.z * scale, b.w * scale);
  *(short8*)&wcat[(size_t)row * 1024 + col] = p.s8;
}

// ---------------------------------------------------------------------------
// Projection (R5 structure, best measured): 256 blocks x 512 thr (8 waves,
// 2 row x 4 col). Block = 64 tokens x 192 heads. BK=64. x AND W staged
// through double-buffered LDS via registers; x converted f32->bf16
// in-flight (cvt_pk). Depth-2 prefetch: step s issues loads for s+2,
// commits regs of s+1 to LDS after MFMAs, one barrier per step.
// Outputs: qw,kw [8][2048][64] bf16; vtw [8][64][2048] bf16 in PERMUTED
// key order: token t stored at (t&~31)|((t>>2)&3)<<3|((t>>4)&1)<<2|(t&3).
// ---------------------------------------------------------------------------
struct Stage {
  float4 x0, x1;        // 8 fp32 of x
  short8 w0, w1, w2;    // 3 rows-chunks of W (r, r+64, r+128)
};

__global__ __launch_bounds__(512, 2) void proj_kernel(
    const float* __restrict__ x, const u16* __restrict__ wcat,
    u16* __restrict__ qw, u16* __restrict__ kw, u16* __restrict__ vtw)
{
  const int tid  = threadIdx.x;
  const int lane = tid & 63;
  const int w    = tid >> 6;
  const int lr   = lane & 15, lg = lane >> 4;
  const int wr   = w >> 2, wc = w & 3;   // 2x4 wave grid
  const int row0 = blockIdx.x * 64;

  __shared__ u16 lX[2][64 * 64];    // 2 x 8KB
  __shared__ u16 lW[2][192 * 64];   // 2 x 24KB

  // staging geometry: thread -> (row tid>>3, col (tid&7)*8)
  const int sr = tid >> 3;              // 0..63
  const int sc = (tid & 7) * 8;
  const float* xp = x    + (size_t)(row0 + sr) * 1024 + sc;
  const u16*   wp = wcat + (size_t)sr * 1024 + sc;
  const int sIdx = (sr * 64 + sc) ^ ((sr & 7) << 3);   // same swizzle all 3 W rows

  const f32x4 vzero = {0.f, 0.f, 0.f, 0.f};
  f32x4 acc[2][3];
#pragma unroll
  for (int m = 0; m < 2; ++m)
#pragma unroll
    for (int c = 0; c < 3; ++c) acc[m][c] = vzero;

  auto issue = [&](Stage& S, int k0) {
    S.x0 = *(const float4*)(xp + k0);
    S.x1 = *(const float4*)(xp + k0 + 4);
    S.w0 = *(const short8*)(wp + k0);
    S.w1 = *(const short8*)(wp + k0 + 65536);    // +64 rows
    S.w2 = *(const short8*)(wp + k0 + 131072);   // +128 rows
  };
  auto commit = [&](const Stage& S, int buf) {
    PackU p;
    p.u[0] = cvt_pk_bf16(S.x0.x, S.x0.y);
    p.u[1] = cvt_pk_bf16(S.x0.z, S.x0.w);
    p.u[2] = cvt_pk_bf16(S.x1.x, S.x1.y);
    p.u[3] = cvt_pk_bf16(S.x1.z, S.x1.w);
    *(short8*)&lX[buf][sIdx]        = p.s8;
    *(short8*)&lW[buf][sIdx]        = S.w0;
    *(short8*)&lW[buf][sIdx + 4096] = S.w1;
    *(short8*)&lW[buf][sIdx + 8192] = S.w2;
  };
  auto computeStep = [&](int buf) {
    short8 af[2][2], wf[3][2];
#pragma unroll
    for (int m = 0; m < 2; ++m) {
      const int ar = wr * 32 + m * 16 + lr;
#pragma unroll
      for (int ks = 0; ks < 2; ++ks)
        af[m][ks] = *(const short8*)&lX[buf][(ar * 64 + ks * 32 + lg * 8) ^ ((ar & 7) << 3)];
    }
#pragma unroll
    for (int c = 0; c < 3; ++c) {
      const int nr = wc * 48 + c * 16 + lr;
#pragma unroll
      for (int ks = 0; ks < 2; ++ks)
        wf[c][ks] = *(const short8*)&lW[buf][(nr * 64 + ks * 32 + lg * 8) ^ ((nr & 7) << 3)];
    }
#pragma unroll
    for (int m = 0; m < 2; ++m)
#pragma unroll
      for (int c = 0; c < 3; ++c) {
        acc[m][c] = mfma16(af[m][0], wf[c][0], acc[m][c]);
        acc[m][c] = mfma16(af[m][1], wf[c][1], acc[m][c]);
      }
  };

  Stage A, B;
  issue(A, 0);
  issue(B, 64);
  commit(A, 0);
  __syncthreads();

  for (int it = 0; it < 8; ++it) {
    const int s = 2 * it;
    // ---- even step s: LDS buf0 holds s; regB holds s+1 ----
    if (it < 7) issue(A, (s + 2) * 64);
    __builtin_amdgcn_sched_barrier(0);
    computeStep(0);
    commit(B, 1);
    __syncthreads();
    // ---- odd step s+1: LDS buf1 holds s+1; regA holds s+2 ----
    if (it < 7) issue(B, (s + 3) * 64);
    __builtin_amdgcn_sched_barrier(0);
    computeStep(1);
    if (it < 7) {
      commit(A, 0);
    }
    __syncthreads();
  }

  const int bb = row0 >> 11;
  const int tb = row0 & 2047;
#pragma unroll
  for (int m = 0; m < 2; ++m) {
    const int tl0 = tb + wr * 32 + 16 * m + 4 * lg;
#pragma unroll
    for (int c = 0; c < 3; ++c) {
      const int n  = wc * 48 + c * 16 + lr;
      const int hd = n & 63;
      if (n < 128) {
        u16* dst = (n < 64) ? qw : kw;
#pragma unroll
        for (int r = 0; r < 4; ++r)
          dst[((size_t)(bb * 2048 + tl0 + r)) * 64 + hd] = f2bf(acc[m][c][r]);
      } else {
        const int posb = (tl0 & ~31) | (((tl0 >> 2) & 3) << 3) | (((tl0 >> 4) & 1) << 2);
        u32* dst = (u32*)&vtw[((size_t)(bb * 64 + hd)) * 2048 + posb];
        dst[0] = cvt_pk_bf16(acc[m][c][0], acc[m][c][1]);
        dst[1] = cvt_pk_bf16(acc[m][c][2], acc[m][c][3]);
      }
    }
  }
}

// ---------------------------------------------------------------------------
// Attention partials (R5 config, verified). grid = 8 batches x 80 blocks,
// 256 thr. Block = q-group j (64 rows = 4 waves x 16-row strips), KV chunk
// of <=8 64-key tiles staged in LDS (dbuf, XOR-swizzled), shared by the 4
// waves. Swapped QK (A=K, B=Q): lane holds S[key=16c+4lg+r][q=lr].
// Static-max softmax: P = exp2(S) (Wq pre-scaled by log2e/32), per-lane
// scalar lsum. PV: A=V(perm layout), B=P packed lane-locally. Chunked
// groups write unnormalized partials; single-chunk groups write directly.
// ---------------------------------------------------------------------------
__global__ __launch_bounds__(256, 2) void attn_kernel(
    const u16* __restrict__ qw, const u16* __restrict__ kw,
    const u16* __restrict__ vtw, float* __restrict__ out,
    float* __restrict__ Opart, float* __restrict__ lpart)
{
  const int tid  = threadIdx.x;
  const int lane = tid & 63;
  const int sid  = tid >> 6;           // strip 0..3
  const int lr   = lane & 15, lg = lane >> 4;
  const int bid  = blockIdx.x;
  const int b    = bid / 80;
  const int g    = bid % 80;

  int j, ch, nch;
  if (g < 8)       { j = g;                ch = 0;          nch = 1; }
  else if (g < 24) { int u = g - 8;  j = 8  + (u >> 1); ch = u & 1;  nch = 2; }
  else if (g < 48) { int u = g - 24; j = 16 + u / 3;    ch = u % 3;  nch = 3; }
  else             { int u = g - 48; j = 24 + (u >> 2); ch = u & 3;  nch = 4; }
  const int kt0 = ch * 8;
  const int kt1 = (kt0 + 8 < j + 1) ? (kt0 + 8) : (j + 1);
  const int q0r = j * 64 + sid * 16;

  __shared__ u16 lK[2][64 * 64];
  __shared__ u16 lV[2][64 * 64];

  const size_t qoff = ((size_t)(b * 2048 + q0r + lr)) * 64 + lg * 8;
  const short8 qa = *(const short8*)(qw + qoff);
  const short8 qb = *(const short8*)(qw + qoff + 32);

  const f32x4 vzero = {0.f, 0.f, 0.f, 0.f};
  f32x4 o[4];
#pragma unroll
  for (int i = 0; i < 4; ++i) o[i] = vzero;
  float lsum = 0.f;

  // staging geometry: 512 chunks per matrix, 2 per thread
  const int sr0 = tid >> 3;            // 0..31 (i=1 adds 32)
  const int sc0 = (tid & 7) * 8;
  const int la0 = (sr0 * 64 + sc0) ^ ((sr0 & 7) << 3);

  short8 kst[2], vst[2];
  {
    const int kb = kt0 * 64;
#pragma unroll
    for (int i = 0; i < 2; ++i) {
      const int r = sr0 + i * 32;
      kst[i] = *(const short8*)(kw  + ((size_t)(b * 2048 + kb + r)) * 64 + sc0);
      vst[i] = *(const short8*)(vtw + ((size_t)(b * 64 + r)) * 2048 + kb + sc0);
    }
#pragma unroll
    for (int i = 0; i < 2; ++i) {
      *(short8*)&lK[0][la0 + i * 2048] = kst[i];
      *(short8*)&lV[0][la0 + i * 2048] = vst[i];
    }
  }
  __syncthreads();

  for (int kt = kt0; kt < kt1; ++kt) {
    const int cur = (kt - kt0) & 1;
    if (kt + 1 < kt1) {
      const int kb = (kt + 1) * 64;
#pragma unroll
      for (int i = 0; i < 2; ++i) {
        const int r = sr0 + i * 32;
        kst[i] = *(const short8*)(kw  + ((size_t)(b * 2048 + kb + r)) * 64 + sc0);
        vst[i] = *(const short8*)(vtw + ((size_t)(b * 64 + r)) * 2048 + kb + sc0);
      }
    }
    // QK^T (swapped): s4[c][r] = S[key = 64kt+16c+4lg+r][q = q0r+lr]
    f32x4 s4[4];
#pragma unroll
    for (int c = 0; c < 4; ++c) {
      const int row = 16 * c + lr;
      const short8 kf0 = *(const short8*)&lK[cur][(row * 64 + lg * 8) ^ ((row & 7) << 3)];
      const short8 kf1 = *(const short8*)&lK[cur][(row * 64 + 32 + lg * 8) ^ ((row & 7) << 3)];
      f32x4 z = vzero;
      z = mfma16(kf0, qa, z);
      z = mfma16(kf1, qb, z);
      s4[c] = z;
    }
    if (kt == j) {   // causal mask on the diagonal tile
#pragma unroll
      for (int c = 0; c < 4; ++c)
#pragma unroll
        for (int r = 0; r < 4; ++r)
          if (16 * c + 4 * lg + r > sid * 16 + lr) s4[c][r] = -1e30f;
    }
    // exp2 + lane-local row-sum accumulation
#pragma unroll
    for (int c = 0; c < 4; ++c)
#pragma unroll
      for (int r = 0; r < 4; ++r) {
        const float e = __builtin_amdgcn_exp2f(s4[c][r]);
        s4[c][r] = e;
        lsum += e;
      }
    // pack P lane-locally: pb0 = keys of c=0,1 ; pb1 = keys of c=2,3
    PackU p0, p1;
    p0.u[0] = cvt_pk_bf16(s4[0][0], s4[0][1]);
    p0.u[1] = cvt_pk_bf16(s4[0][2], s4[0][3]);
    p0.u[2] = cvt_pk_bf16(s4[1][0], s4[1][1]);
    p0.u[3] = cvt_pk_bf16(s4[1][2], s4[1][3]);
    p1.u[0] = cvt_pk_bf16(s4[2][0], s4[2][1]);
    p1.u[1] = cvt_pk_bf16(s4[2][2], s4[2][3]);
    p1.u[2] = cvt_pk_bf16(s4[3][0], s4[3][1]);
    p1.u[3] = cvt_pk_bf16(s4[3][2], s4[3][3]);
    const short8 pb0 = p0.s8, pb1 = p1.s8;
    // PV: o[cd] over d = 16cd+4lg+r
#pragma unroll
    for (int cd = 0; cd < 4; ++cd) {
      const int row = 16 * cd + lr;
      const short8 vf0 = *(const short8*)&lV[cur][(row * 64 + lg * 8) ^ ((row & 7) << 3)];
      const short8 vf1 = *(const short8*)&lV[cur][(row * 64 + 32 + lg * 8) ^ ((row & 7) << 3)];
      o[cd] = mfma16(vf0, pb0, o[cd]);
      o[cd] = mfma16(vf1, pb1, o[cd]);
    }
    if (kt + 1 < kt1) {
#pragma unroll
      for (int i = 0; i < 2; ++i) {
        *(short8*)&lK[cur ^ 1][la0 + i * 2048] = kst[i];
        *(short8*)&lV[cur ^ 1][la0 + i * 2048] = vst[i];
      }
      __syncthreads();
    }
  }

  lsum += __shfl_xor(lsum, 16, 64);
  lsum += __shfl_xor(lsum, 32, 64);

  if (nch == 1) {
    const float inv = 1.0f / lsum;
    float* op = out + ((size_t)(b * 2048 + q0r + lr)) * 64;
#pragma unroll
    for (int cd = 0; cd < 4; ++cd) {
      f32x4 v = o[cd] * inv;
      *(f32x4*)(op + 16 * cd + 4 * lg) = v;
    }
  } else {
    int pb;
    if (j < 16)      pb = 2 * (j - 8);
    else if (j < 24) pb = 16 + 3 * (j - 16);
    else             pb = 40 + 4 * (j - 24);
    const int pidx = b * 72 + pb + ch;
    float* op = Opart + ((size_t)(pidx * 64) + sid * 16 + lr) * 64;
#pragma unroll
    for (int cd = 0; cd < 4; ++cd)
      *(f32x4*)(op + 16 * cd + 4 * lg) = o[cd];
    if (lg == 0) lpart[pidx * 64 + sid * 16 + lr] = lsum;
  }
}

// ---------------------------------------------------------------------------
// Merge partials for chunked groups (j >= 8). 768 blocks x 256 thr.
// thread -> (merged q-row, 4-wide d quad); out = sum(Opart)/sum(l).
// ---------------------------------------------------------------------------
__global__ __launch_bounds__(256) void merge_kernel(
    const float* __restrict__ Opart, const float* __restrict__ lpart,
    float* __restrict__ out)
{
  const int t = blockIdx.x * 256 + threadIdx.x;
  const int ridx = t >> 4;           // 0..12287
  const int dq = (t & 15) * 4;
  const int b = ridx / 1536;
  const int r2 = ridx % 1536;
  const int jj = r2 >> 6;            // 0..23 -> j = jj+8
  const int ql = r2 & 63;
  int pb, nch;
  if (jj < 8)       { pb = 2 * jj;            nch = 2; }
  else if (jj < 16) { pb = 16 + 3 * (jj - 8); nch = 3; }
  else              { pb = 40 + 4 * (jj - 16); nch = 4; }
  const int base = b * 72 + pb;
  f32x4 acc = {0.f, 0.f, 0.f, 0.f};
  float l = 0.f;
  for (int c = 0; c < nch; ++c) {
    acc += *(const f32x4*)(Opart + (((size_t)(base + c) * 64 + ql) * 64 + dq));
    l += lpart[(base + c) * 64 + ql];
  }
  const float inv = 1.0f / l;
  *(f32x4*)&out[((size_t)(b * 2048 + (jj + 8) * 64 + ql)) * 64 + dq] = acc * inv;
}

extern "C" void kernel_launch(void* const* d_in, const int* in_sizes, int n_in,
                              void* d_out, int out_size, void* d_ws, size_t ws_size,
                              hipStream_t stream) {
  // setup_inputs order: x, Wk, Wq, Wv
  const float* x  = (const float*)d_in[0];
  const float* Wk = (const float*)d_in[1];
  const float* Wq = (const float*)d_in[2];
  const float* Wv = (const float*)d_in[3];

  u16* wcat = (u16*)d_ws;                        // 192*1024       = 196608
  u16* qw   = wcat + 196608;                     // 16384*64
  u16* kw   = qw + 1048576;
  u16* vtw  = kw + 1048576;
  float* Opart = (float*)(vtw + 1048576);        // 576*64*64 f32
  float* lpart = Opart + 2359296;                // 576*64 f32
  float* out = (float*)d_out;

  wconv_kernel<<<dim3(96),  dim3(256), 0, stream>>>(Wk, Wq, Wv, wcat);
  proj_kernel <<<dim3(256), dim3(512), 0, stream>>>(x, wcat, qw, kw, vtw);
  attn_kernel <<<dim3(640), dim3(256), 0, stream>>>(qw, kw, vtw, out, Opart, lpart);
  merge_kernel<<<dim3(768), dim3(256), 0, stream>>>(Opart, lpart, out);
}